// Round 1
// 552.596 us; speedup vs baseline: 1.0556x; 1.0556x over previous
//
#include <hip/hip_runtime.h>
#include <stdint.h>

#define DEV static __device__ __forceinline__

typedef __attribute__((ext_vector_type(8))) __bf16 bf16x8;
typedef __attribute__((ext_vector_type(4))) float f32x4;
typedef __attribute__((ext_vector_type(16))) float f32x16;

// ---------- bf16 helpers ----------
DEV float b2f(unsigned short u) {
    union { unsigned int i; float f; } v; v.i = ((unsigned int)u) << 16; return v.f;
}
DEV unsigned short f2b(float f) {
    unsigned int u = __builtin_bit_cast(unsigned int, f);
    unsigned int r = (u + 0x7FFFu + ((u >> 16) & 1u)) >> 16;  // RNE
    return (unsigned short)r;
}
DEV f32x4 mfma16(bf16x8 a, bf16x8 b, f32x4 c) {
    return __builtin_amdgcn_mfma_f32_16x16x32_bf16(a, b, c, 0, 0, 0);
}
DEV f32x16 mfma32(bf16x8 a, bf16x8 b, f32x16 c) {
    return __builtin_amdgcn_mfma_f32_32x32x16_bf16(a, b, c, 0, 0, 0);
}

// ---------- async global->LDS, 16B per lane ----------
DEV void gload16(const void* g, void* l) {
    __builtin_amdgcn_global_load_lds(
        (const __attribute__((address_space(1))) void*)g,
        (__attribute__((address_space(3))) void*)l, 16, 0, 0);
}

// ============ kernel 0: fp32 -> bf16 copy (n multiple of 2048) ==============
__global__ __launch_bounds__(256) void k_cvt(
    const float* __restrict__ src, unsigned short* __restrict__ dst)
{
    long i = ((long)blockIdx.x * 256 + threadIdx.x) * 8;
    float4 a = *(const float4*)(src + i);
    float4 b = *(const float4*)(src + i + 4);
    union { uint4 v; unsigned short s[8]; } o;
    o.s[0] = f2b(a.x); o.s[1] = f2b(a.y); o.s[2] = f2b(a.z); o.s[3] = f2b(a.w);
    o.s[4] = f2b(b.x); o.s[5] = f2b(b.y); o.s[6] = f2b(b.z); o.s[7] = f2b(b.w);
    *(uint4*)(dst + i) = o.v;
}

// ================== kernel 1: RMSNorm of hidden -> u (bf16) =================
__global__ __launch_bounds__(256) void k_rmsnorm_in(
    const float* __restrict__ h, const float* __restrict__ w,
    unsigned short* __restrict__ u)
{
    int row = blockIdx.x, t = threadIdx.x;
    const float* hp = h + (long)row * 2048 + t * 8;
    float4 a = *(const float4*)hp;
    float4 b = *(const float4*)(hp + 4);
    float x[8] = {a.x, a.y, a.z, a.w, b.x, b.y, b.z, b.w};
    float ss = 0.f;
#pragma unroll
    for (int i = 0; i < 8; i++) ss += x[i] * x[i];
#pragma unroll
    for (int o = 32; o > 0; o >>= 1) ss += __shfl_down(ss, o);
    __shared__ float red[4];
    if ((t & 63) == 0) red[t >> 6] = ss;
    __syncthreads();
    float tot = red[0] + red[1] + red[2] + red[3];
    float scale = rsqrtf(tot * (1.0f / 2048.0f) + 1e-5f);
    float4 wa = *(const float4*)(w + t * 8);
    float4 wb = *(const float4*)(w + t * 8 + 4);
    float wv[8] = {wa.x, wa.y, wa.z, wa.w, wb.x, wb.y, wb.z, wb.w};
    union { uint4 v; unsigned short s[8]; } ow;
#pragma unroll
    for (int i = 0; i < 8; i++) ow.s[i] = f2b(x[i] * scale * wv[i]);
    *(uint4*)(u + (long)row * 2048 + t * 8) = ow.v;
}

// ================== GEMM: C[MxN] = A[MxK] * B[NxK]^T (bf16 in, fp32 acc) ====
// 128x128 tile, BK=64 (128B LDS rows), 4 waves (2x2 of 64x64), 32x32x16 MFMA.
// LDS bank-conflict fix (T2): linear global_load_lds dest + pre-swizzled
// per-lane global source chunk (c16 ^ (row&7)) + same XOR on ds_read side.
// Quarter-wave reads land 2 lanes/slot across all 8 16B slots -> conflict-free.
// Supertile swizzle: 8 M-tiles per supercolumn for L2 reuse of B.
// EPI 0: store bf16 to Cb.  EPI 1: store fp32 (acc + fp32 Res) to Cf.
template <int EPI>
__global__ __launch_bounds__(256) void k_gemm_bt(
    const unsigned short* __restrict__ A, const unsigned short* __restrict__ Bm,
    int K, int nvalid, unsigned short* __restrict__ Cb, float* __restrict__ Cf,
    int ldc, const float* __restrict__ Res)
{
    __shared__ __align__(16) unsigned short sA[128 * 64];
    __shared__ __align__(16) unsigned short sB[128 * 64];
    int t = threadIdx.x;
    int w = t >> 6, L = t & 63;

    // ---- supertile swizzle (gy must be multiple of 8; 32 here) ----
    int flat = blockIdx.y * gridDim.x + blockIdx.x;
    int per = gridDim.x * 8;
    int strip = flat / per;
    int rem = flat - strip * per;
    long m0 = (long)(strip * 8 + (rem & 7)) * 128;
    long n0 = (long)(rem >> 3) * 128;

    // ---- staging: linear LDS dest, inverse-swizzled global source ----
    // round i stages LDS rows [i*32, i*32+32); thread t: row=i*32+(t>>3),
    // 16B chunk (t&7); source chunk = (t&7) ^ (row&7)  (row&7 == (t>>3)&7).
    int rloc = t >> 3;               // 0..31
    int c16  = t & 7;                // 16B chunk within 128B row
    int csw  = c16 ^ (rloc & 7);     // pre-swizzled source chunk
    const unsigned short* gAp[4];
    const unsigned short* gBp[4];
#pragma unroll
    for (int i = 0; i < 4; i++) {
        gAp[i] = A + (m0 + i * 32 + rloc) * (long)K + csw * 8;
        long rb = n0 + i * 32 + rloc;
        if (rb >= nvalid) rb = nvalid - 1;
        gBp[i] = Bm + rb * (long)K + csw * 8;
    }
    unsigned short* lA = sA + t * 8;   // + i*2048 shorts per round
    unsigned short* lB = sB + t * 8;

    int mw = (w >> 1) * 64, nw = (w & 1) * 64;
    // 32x32x16 A/B fragment: m(n)=lane&31, k=(lane>>5)*8+j
    int rowA = mw + (L & 31), rowB = nw + (L & 31);
    int swA = (rowA & 7) << 4, swB = (rowB & 7) << 4;
    int q16 = (L >> 5) * 16;          // lane's k-chunk byte offset
    const char* pA = (const char*)sA + rowA * 128;
    const char* pB = (const char*)sB + rowB * 128;

    f32x16 acc[2][2];
#pragma unroll
    for (int ti = 0; ti < 2; ti++)
#pragma unroll
        for (int tj = 0; tj < 2; tj++)
#pragma unroll
            for (int r = 0; r < 16; r++) acc[ti][tj][r] = 0.f;

    for (int kt = 0; kt < K; kt += 64) {
#pragma unroll
        for (int i = 0; i < 4; i++) {
            gload16(gAp[i], lA + i * 2048);
            gload16(gBp[i], lB + i * 2048);
            gAp[i] += 64; gBp[i] += 64;
        }
        __syncthreads();
#pragma unroll
        for (int kk = 0; kk < 4; kk++) {
            bf16x8 af[2], bf[2];
#pragma unroll
            for (int ti = 0; ti < 2; ti++)
                af[ti] = *(const bf16x8*)(pA + ti * 4096 + ((q16 + kk * 32) ^ swA));
#pragma unroll
            for (int tj = 0; tj < 2; tj++)
                bf[tj] = *(const bf16x8*)(pB + tj * 4096 + ((q16 + kk * 32) ^ swB));
#pragma unroll
            for (int ti = 0; ti < 2; ti++)
#pragma unroll
                for (int tj = 0; tj < 2; tj++)
                    acc[ti][tj] = mfma32(af[ti], bf[tj], acc[ti][tj]);
        }
        __syncthreads();
    }
    // C/D layout (m74/m101): col = lane&31, row = (reg&3) + 8*(reg>>2) + 4*(lane>>5)
    int colL = L & 31;
    int rL = (L >> 5) * 4;
#pragma unroll
    for (int ti = 0; ti < 2; ti++)
#pragma unroll
        for (int tj = 0; tj < 2; tj++) {
            long c = n0 + nw + tj * 32 + colL;
            if (c >= nvalid) continue;
#pragma unroll
            for (int r = 0; r < 16; r++) {
                long row = m0 + mw + ti * 32 + (r & 3) + 8 * (r >> 2) + rL;
                float v = acc[ti][tj][r];
                if (EPI == 0) Cb[row * ldc + c] = f2b(v);
                else          Cf[row * ldc + c] = v + Res[row * ldc + c];
            }
        }
}

// ======= kernel 4: depthwise causal conv(4) + bias + silu over xBC ==========
__global__ __launch_bounds__(128) void k_conv(
    const unsigned short* __restrict__ zx, const float* __restrict__ cw,
    const float* __restrict__ cb, unsigned short* __restrict__ xbc)
{
    int c = blockIdx.x * 128 + threadIdx.x;   // 0..4223
    int b = blockIdx.z;
    int l0 = blockIdx.y * 64;
    float w0 = cw[c * 4 + 0], w1 = cw[c * 4 + 1];
    float w2 = cw[c * 4 + 2], w3 = cw[c * 4 + 3];
    float bias = cb[c];
    const unsigned short* src = zx + ((long)b * 2048) * 8384 + 4096 + c;
    float xm3 = (l0 >= 3) ? b2f(src[(long)(l0 - 3) * 8384]) : 0.f;
    float xm2 = (l0 >= 2) ? b2f(src[(long)(l0 - 2) * 8384]) : 0.f;
    float xm1 = (l0 >= 1) ? b2f(src[(long)(l0 - 1) * 8384]) : 0.f;
    const unsigned short* s2 = src + (long)l0 * 8384;
    unsigned short* dst = xbc + ((long)(b * 2048 + l0)) * 4224 + c;
#pragma unroll 8
    for (int i = 0; i < 64; i++) {
        float xl = b2f(*s2); s2 += 8384;
        float a = xm3 * w0 + xm2 * w1 + xm1 * w2 + xl * w3 + bias;
        a = a / (1.f + expf(-a));      // silu
        *dst = f2b(a); dst += 4224;
        xm3 = xm2; xm2 = xm1; xm1 = xl;
    }
}

// ============ kernel 5a: per-chunk state via MFMA (pass 1) ==================
__global__ __launch_bounds__(256) void k_chunk_state_mfma(
    const unsigned short* __restrict__ xbc, const unsigned short* __restrict__ zxdt,
    const float* __restrict__ dt_bias, const float* __restrict__ A_log,
    unsigned short* __restrict__ Sbuf, float* __restrict__ dAtot)
{
    int blk = blockIdx.x;
    int c = blk & 7, bh = blk >> 3;
    int b = bh >> 6, h = bh & 63;
    int tid = threadIdx.x;
    int w = tid >> 6, L = tid & 63;
    int quad = L >> 4, col = L & 15;
    int rowBlk = (w >> 1) * 32, colBlk = (w & 1) * 32;
    __shared__ __align__(16) unsigned short sXp[64 * 72];  // X^T (p,t)
    __shared__ __align__(16) unsigned short sBn[64 * 72];  // scaled B^T (n,t)
    __shared__ float sdt[64], sL[64];
    float Ah = expf(A_log[h]);
    float dtb = dt_bias[h];
    f32x4 acc[2][2];
#pragma unroll
    for (int ti = 0; ti < 2; ti++)
#pragma unroll
        for (int tj = 0; tj < 2; tj++) acc[ti][tj] = (f32x4){0.f, 0.f, 0.f, 0.f};
    float sumL = 0.f;

    for (int sub = 0; sub < 4; sub++) {
        int l0 = c * 256 + sub * 64;
        // stage X transposed -> (p,t)
        {
            int t = tid >> 2, pc = tid & 3;
            const unsigned short* gX = xbc + (long)(b * 2048 + l0 + t) * 4224 + h * 64 + pc * 16;
            union { uint4 v; unsigned short s[8]; } x0, x1;
            x0.v = *(const uint4*)gX; x1.v = *(const uint4*)(gX + 8);
#pragma unroll
            for (int j = 0; j < 8; j++) {
                sXp[(pc * 16 + j) * 72 + t] = x0.s[j];
                sXp[(pc * 16 + 8 + j) * 72 + t] = x1.s[j];
            }
        }
        // dt, cumulative log-decay (wave 0)
        if (tid < 64) {
            float raw = b2f(zxdt[((long)(b * 2048 + l0 + tid)) * 8384 + 8320 + h]) + dtb;
            float dtv = (raw > 20.f) ? raw : log1pf(expf(raw));
            float cum = dtv;
#pragma unroll
            for (int off = 1; off < 64; off <<= 1) {
                float v = __shfl_up(cum, off);
                if (tid >= off) cum += v;
            }
            sdt[tid] = dtv;
            sL[tid] = -Ah * cum;
        }
        __syncthreads();
        float Lend = sL[63];
        // stage B transposed & scaled: Bn[n][t] = B[t][n] * dt_t * exp(Lend - L_t)
        {
            int t = tid >> 2, nc = tid & 3;
            float wt = sdt[t] * __expf(Lend - sL[t]);
            const unsigned short* gB = xbc + (long)(b * 2048 + l0 + t) * 4224 + 4096 + nc * 16;
            union { uint4 v; unsigned short s[8]; } x0, x1;
            x0.v = *(const uint4*)gB; x1.v = *(const uint4*)(gB + 8);
#pragma unroll
            for (int j = 0; j < 8; j++) {
                sBn[(nc * 16 + j) * 72 + t] = f2b(b2f(x0.s[j]) * wt);
                sBn[(nc * 16 + 8 + j) * 72 + t] = f2b(b2f(x1.s[j]) * wt);
            }
        }
        __syncthreads();
        float e_end = __expf(Lend);
        sumL += Lend;
#pragma unroll
        for (int ti = 0; ti < 2; ti++)
#pragma unroll
            for (int tj = 0; tj < 2; tj++)
#pragma unroll
                for (int r = 0; r < 4; r++) acc[ti][tj][r] *= e_end;
#pragma unroll
        for (int kb = 0; kb < 2; kb++) {
            bf16x8 ax[2], bx[2];
#pragma unroll
            for (int ti = 0; ti < 2; ti++)
                ax[ti] = *(const bf16x8*)(sXp + (rowBlk + ti * 16 + col) * 72 + kb * 32 + quad * 8);
#pragma unroll
            for (int tj = 0; tj < 2; tj++)
                bx[tj] = *(const bf16x8*)(sBn + (colBlk + tj * 16 + col) * 72 + kb * 32 + quad * 8);
#pragma unroll
            for (int ti = 0; ti < 2; ti++)
#pragma unroll
                for (int tj = 0; tj < 2; tj++)
                    acc[ti][tj] = mfma16(ax[ti], bx[tj], acc[ti][tj]);
        }
        __syncthreads();
    }
#pragma unroll
    for (int ti = 0; ti < 2; ti++)
#pragma unroll
        for (int tj = 0; tj < 2; tj++)
#pragma unroll
            for (int r = 0; r < 4; r++) {
                int p = rowBlk + ti * 16 + quad * 4 + r;
                int n = colBlk + tj * 16 + col;
                Sbuf[(long)blk * 4096 + p * 64 + n] = f2b(acc[ti][tj][r]);
            }
    if (tid == 0) dAtot[blk] = __expf(sumL);
}

// ============ kernel 5b: SSD intra-chunk via MFMA (pass 2) ==================
__global__ __launch_bounds__(256) void k_scan_chunk_mfma(
    const unsigned short* __restrict__ xbc, const unsigned short* __restrict__ zxdt,
    const float* __restrict__ dt_bias, const float* __restrict__ A_log,
    const float* __restrict__ Dv,
    const unsigned short* __restrict__ Sbuf, const float* __restrict__ dAtot,
    unsigned short* __restrict__ yout)
{
    int blk = blockIdx.x;
    int c = blk & 7, bh = blk >> 3;
    int b = bh >> 6, h = bh & 63;
    int tid = threadIdx.x;
    int w = tid >> 6, L = tid & 63;
    int quad = L >> 4, col = L & 15;
    int rowBlk = (w >> 1) * 32, colBlk = (w & 1) * 32;
    __shared__ __align__(16) unsigned short sCm[64 * 72];    // C (s,n)
    __shared__ __align__(16) unsigned short sBtMs[64 * 72];  // B (t,n) -> reused as M (s,t)
    __shared__ __align__(16) unsigned short sXp[64 * 72];    // X^T (p,t)
    __shared__ __align__(16) unsigned short sBn[64 * 72];    // scaled B^T (n,t)
    __shared__ __align__(16) unsigned short sHb[64 * 72];    // H (p,n) bf16
    __shared__ float sdt[64], sL[64], sEs[64];
    float Ah = expf(A_log[h]);
    float dtb = dt_bias[h];
    float Dh = Dv[h];

    f32x4 acc_h[2][2];
#pragma unroll
    for (int ti = 0; ti < 2; ti++)
#pragma unroll
        for (int tj = 0; tj < 2; tj++) acc_h[ti][tj] = (f32x4){0.f, 0.f, 0.f, 0.f};
    int sb = bh * 8;
    for (int j = 0; j < c; j++) {
        float d = dAtot[sb + j];
        const unsigned short* Sp = Sbuf + (long)(sb + j) * 4096;
#pragma unroll
        for (int ti = 0; ti < 2; ti++)
#pragma unroll
            for (int tj = 0; tj < 2; tj++)
#pragma unroll
                for (int r = 0; r < 4; r++) {
                    int p = rowBlk + ti * 16 + quad * 4 + r;
                    int n = colBlk + tj * 16 + col;
                    acc_h[ti][tj][r] = acc_h[ti][tj][r] * d + b2f(Sp[p * 64 + n]);
                }
    }

    for (int sub = 0; sub < 4; sub++) {
        int l0 = c * 256 + sub * 64;
        // (a) stage C (s,n) and B (t,n), stride-72 rows
        {
            int row = tid >> 2, c4 = tid & 3;
            const unsigned short* gR = xbc + (long)(b * 2048 + l0 + row) * 4224;
            uint4 v0 = *(const uint4*)(gR + 4160 + c4 * 8);
            uint4 v1 = *(const uint4*)(gR + 4160 + (c4 + 4) * 8);
            *(uint4*)(sCm + row * 72 + c4 * 8) = v0;
            *(uint4*)(sCm + row * 72 + (c4 + 4) * 8) = v1;
            uint4 w0 = *(const uint4*)(gR + 4096 + c4 * 8);
            uint4 w1 = *(const uint4*)(gR + 4096 + (c4 + 4) * 8);
            *(uint4*)(sBtMs + row * 72 + c4 * 8) = w0;
            *(uint4*)(sBtMs + row * 72 + (c4 + 4) * 8) = w1;
        }
        // stage X transposed
        {
            int t = tid >> 2, pc = tid & 3;
            const unsigned short* gX = xbc + (long)(b * 2048 + l0 + t) * 4224 + h * 64 + pc * 16;
            union { uint4 v; unsigned short s[8]; } x0, x1;
            x0.v = *(const uint4*)gX; x1.v = *(const uint4*)(gX + 8);
#pragma unroll
            for (int j = 0; j < 8; j++) {
                sXp[(pc * 16 + j) * 72 + t] = x0.s[j];
                sXp[(pc * 16 + 8 + j) * 72 + t] = x1.s[j];
            }
        }
        // (b) dt / L / exp(L)
        if (tid < 64) {
            float raw = b2f(zxdt[((long)(b * 2048 + l0 + tid)) * 8384 + 8320 + h]) + dtb;
            float dtv = (raw > 20.f) ? raw : log1pf(expf(raw));
            float cum = dtv;
#pragma unroll
            for (int off = 1; off < 64; off <<= 1) {
                float v = __shfl_up(cum, off);
                if (tid >= off) cum += v;
            }
            sdt[tid] = dtv;
            float l = -Ah * cum;
            sL[tid] = l;
            sEs[tid] = __expf(l);
        }
        __syncthreads();
        float Lend = sL[63];
        // (c) stage scaled-transposed B; write H (bf16) for Ycross
        {
            int t = tid >> 2, nc = tid & 3;
            float wt = sdt[t] * __expf(Lend - sL[t]);
            const unsigned short* gB = xbc + (long)(b * 2048 + l0 + t) * 4224 + 4096 + nc * 16;
            union { uint4 v; unsigned short s[8]; } x0, x1;
            x0.v = *(const uint4*)gB; x1.v = *(const uint4*)(gB + 8);
#pragma unroll
            for (int j = 0; j < 8; j++) {
                sBn[(nc * 16 + j) * 72 + t] = f2b(b2f(x0.s[j]) * wt);
                sBn[(nc * 16 + 8 + j) * 72 + t] = f2b(b2f(x1.s[j]) * wt);
            }
        }
#pragma unroll
        for (int ti = 0; ti < 2; ti++)
#pragma unroll
            for (int tj = 0; tj < 2; tj++)
#pragma unroll
                for (int r = 0; r < 4; r++) {
                    int p = rowBlk + ti * 16 + quad * 4 + r;
                    int n = colBlk + tj * 16 + col;
                    sHb[p * 72 + n] = f2b(acc_h[ti][tj][r]);
                }
        __syncthreads();
        // (d) G = C @ B^T
        f32x4 g[2][2];
#pragma unroll
        for (int ti = 0; ti < 2; ti++)
#pragma unroll
            for (int tj = 0; tj < 2; tj++) g[ti][tj] = (f32x4){0.f, 0.f, 0.f, 0.f};
#pragma unroll
        for (int kb = 0; kb < 2; kb++) {
            bf16x8 ac[2], bc[2];
#pragma unroll
            for (int ti = 0; ti < 2; ti++)
                ac[ti] = *(const bf16x8*)(sCm + (rowBlk + ti * 16 + col) * 72 + kb * 32 + quad * 8);
#pragma unroll
            for (int tj = 0; tj < 2; tj++)
                bc[tj] = *(const bf16x8*)(sBtMs + (colBlk + tj * 16 + col) * 72 + kb * 32 + quad * 8);
#pragma unroll
            for (int ti = 0; ti < 2; ti++)
#pragma unroll
                for (int tj = 0; tj < 2; tj++)
                    g[ti][tj] = mfma16(ac[ti], bc[tj], g[ti][tj]);
        }
        __syncthreads();   // all waves done reading B before overwrite as M
        // (e) mask + decay -> M (s,t) into sBtMs
#pragma unroll
        for (int tj = 0; tj < 2; tj++) {
            int t_idx = colBlk + tj * 16 + col;
            float lt = sL[t_idx], dtt = sdt[t_idx];
#pragma unroll
            for (int ti = 0; ti < 2; ti++)
#pragma unroll
                for (int r = 0; r < 4; r++) {
                    int s_idx = rowBlk + ti * 16 + quad * 4 + r;
                    float m = (t_idx <= s_idx) ? g[ti][tj][r] * dtt * __expf(sL[s_idx] - lt) : 0.f;
                    sBtMs[s_idx * 72 + t_idx] = f2b(m);
                }
        }
        __syncthreads();
        // (f) Y = M @ X + (es*C) @ H^T
        f32x4 yv[2][2];
#pragma unroll
        for (int ti = 0; ti < 2; ti++)
#pragma unroll
            for (int tj = 0; tj < 2; tj++) yv[ti][tj] = (f32x4){0.f, 0.f, 0.f, 0.f};
#pragma unroll
        for (int kb = 0; kb < 2; kb++) {
            bf16x8 am[2], bxp[2];
#pragma unroll
            for (int ti = 0; ti < 2; ti++)
                am[ti] = *(const bf16x8*)(sBtMs + (rowBlk + ti * 16 + col) * 72 + kb * 32 + quad * 8);
#pragma unroll
            for (int tj = 0; tj < 2; tj++)
                bxp[tj] = *(const bf16x8*)(sXp + (colBlk + tj * 16 + col) * 72 + kb * 32 + quad * 8);
#pragma unroll
            for (int ti = 0; ti < 2; ti++)
#pragma unroll
                for (int tj = 0; tj < 2; tj++)
                    yv[ti][tj] = mfma16(am[ti], bxp[tj], yv[ti][tj]);
        }
        float es0 = sEs[rowBlk + col], es1 = sEs[rowBlk + 16 + col];
#pragma unroll
        for (int kb = 0; kb < 2; kb++) {
            bf16x8 acx[2], bhh[2];
#pragma unroll
            for (int ti = 0; ti < 2; ti++) {
                union { bf16x8 v; unsigned short s[8]; } a;
                a.v = *(const bf16x8*)(sCm + (rowBlk + ti * 16 + col) * 72 + kb * 32 + quad * 8);
                float es = ti ? es1 : es0;
#pragma unroll
                for (int j = 0; j < 8; j++) a.s[j] = f2b(b2f(a.s[j]) * es);
                acx[ti] = a.v;
            }
#pragma unroll
            for (int tj = 0; tj < 2; tj++)
                bhh[tj] = *(const bf16x8*)(sHb + (colBlk + tj * 16 + col) * 72 + kb * 32 + quad * 8);
#pragma unroll
            for (int ti = 0; ti < 2; ti++)
#pragma unroll
                for (int tj = 0; tj < 2; tj++)
                    yv[ti][tj] = mfma16(acx[ti], bhh[tj], yv[ti][tj]);
        }
        // (g) H = e_end*H + Xw^T @ B
        float e_end = __expf(Lend);
#pragma unroll
        for (int ti = 0; ti < 2; ti++)
#pragma unroll
            for (int tj = 0; tj < 2; tj++)
#pragma unroll
                for (int r = 0; r < 4; r++) acc_h[ti][tj][r] *= e_end;
#pragma unroll
        for (int kb = 0; kb < 2; kb++) {
            bf16x8 ax[2], bn[2];
#pragma unroll
            for (int ti = 0; ti < 2; ti++)
                ax[ti] = *(const bf16x8*)(sXp + (rowBlk + ti * 16 + col) * 72 + kb * 32 + quad * 8);
#pragma unroll
            for (int tj = 0; tj < 2; tj++)
                bn[tj] = *(const bf16x8*)(sBn + (colBlk + tj * 16 + col) * 72 + kb * 32 + quad * 8);
#pragma unroll
            for (int ti = 0; ti < 2; ti++)
#pragma unroll
                for (int tj = 0; tj < 2; tj++)
                    acc_h[ti][tj] = mfma16(ax[ti], bn[tj], acc_h[ti][tj]);
        }
        // (h) y epilogue: + D*x, store bf16
#pragma unroll
        for (int ti = 0; ti < 2; ti++)
#pragma unroll
            for (int tj = 0; tj < 2; tj++)
#pragma unroll
                for (int r = 0; r < 4; r++) {
                    int s_idx = rowBlk + ti * 16 + quad * 4 + r;
                    int p = colBlk + tj * 16 + col;
                    float xv = b2f(sXp[p * 72 + s_idx]);
                    float yo = yv[ti][tj][r] + Dh * xv;
                    yout[((long)(b * 2048 + l0 + s_idx)) * 8384 + 4096 + h * 64 + p] = f2b(yo);
                }
        __syncthreads();   // protect LDS reuse next sub-chunk
    }
}

// ====== kernel 6: gated RMSNorm: y2 = rmsnorm(y * silu(z)) * norm_w (bf16) ==
__global__ __launch_bounds__(256) void k_gatenorm(
    const unsigned short* __restrict__ zx, const float* __restrict__ nw,
    unsigned short* __restrict__ y2)
{
    int row = blockIdx.x, t = threadIdx.x;
    const unsigned short* zr = zx + (long)row * 8384;
    float v[16]; float ss = 0.f;
#pragma unroll
    for (int i = 0; i < 16; i++) {
        int c = t + i * 256;
        float z = b2f(zr[c]);
        float y = b2f(zr[4096 + c]);
        float g = y * (z / (1.f + expf(-z)));
        v[i] = g; ss += g * g;
    }
#pragma unroll
    for (int o = 32; o > 0; o >>= 1) ss += __shfl_down(ss, o);
    __shared__ float red[4];
    if ((t & 63) == 0) red[t >> 6] = ss;
    __syncthreads();
    float tot = red[0] + red[1] + red[2] + red[3];
    float scale = rsqrtf(tot * (1.0f / 4096.0f) + 1e-5f);
#pragma unroll
    for (int i = 0; i < 16; i++) {
        int c = t + i * 256;
        y2[(long)row * 4096 + c] = f2b(v[i] * scale * nw[c]);
    }
}

// ============================= launcher =====================================
extern "C" void kernel_launch(void* const* d_in, const int* in_sizes, int n_in,
                              void* d_out, int out_size, void* d_ws, size_t ws_size,
                              hipStream_t stream)
{
    const float* h    = (const float*)d_in[0]; // (2,2048,2048)
    const float* rmsw = (const float*)d_in[1]; // (2048)
    const float* w1   = (const float*)d_in[2]; // (8384,2048)
    const float* cw   = (const float*)d_in[3]; // (4224,4)
    const float* cbp  = (const float*)d_in[4]; // (4224)
    const float* dtb  = (const float*)d_in[5]; // (64)
    const float* alog = (const float*)d_in[6]; // (64)
    const float* Dv   = (const float*)d_in[7]; // (64)
    const float* nw   = (const float*)d_in[8]; // (4096)
    const float* w2   = (const float*)d_in[9]; // (2048,4096)

    char* ws = (char*)d_ws;
    // ws layout (peak 120,061,952 B — identical to prior passing layout):
    //   [0, 68681728): zx bf16 4096x8384 (scan writes y into cols 4096..8192)
    //   [68681728, 103284736): w1b bf16 -> xbc bf16 4096x4224 -> y2 bf16
    //   [103284736, 111673344): Sbuf bf16 1024x4096
    //   [111673344, +4096):     dAt fp32 1024
    //   [103284736, 120061952): u before GEMM1; w2b after scan (Sbuf/dAt dead)
    unsigned short* zx    = (unsigned short*)ws;
    unsigned short* w1b   = (unsigned short*)(ws + 68681728L);
    unsigned short* xbc   = (unsigned short*)(ws + 68681728L);
    unsigned short* y2    = (unsigned short*)(ws + 68681728L);
    unsigned short* u     = (unsigned short*)(ws + 103284736L);
    unsigned short* Sbuf  = (unsigned short*)(ws + 103284736L);
    float*          dAt   = (float*)(ws + 111673344L);
    unsigned short* w2b   = (unsigned short*)(ws + 103284736L);
    float* outp = (float*)d_out;

    k_rmsnorm_in<<<4096, 256, 0, stream>>>(h, rmsw, u);
    k_cvt<<<8384, 256, 0, stream>>>(w1, w1b);
    // zx = u @ w1b^T : M=4096, N=8384 (66 tiles, clamped), K=2048
    k_gemm_bt<0><<<dim3(66, 32), 256, 0, stream>>>(u, w1b, 2048, 8384, zx, nullptr, 8384, nullptr);
    k_conv<<<dim3(33, 32, 2), 128, 0, stream>>>(zx, cw, cbp, xbc);
    k_chunk_state_mfma<<<1024, 256, 0, stream>>>(xbc, zx, dtb, alog, Sbuf, dAt);
    k_scan_chunk_mfma<<<1024, 256, 0, stream>>>(xbc, zx, dtb, alog, Dv, Sbuf, dAt, zx);
    k_gatenorm<<<4096, 256, 0, stream>>>(zx, nw, y2);
    k_cvt<<<4096, 256, 0, stream>>>(w2, w2b);
    // out = y2 @ w2b^T + residual : M=4096, N=2048, K=4096, fp32 out
    k_gemm_bt<1><<<dim3(16, 32), 256, 0, stream>>>(y2, w2b, 4096, 2048, nullptr, outp, 2048, h);
}

// Round 2
// 531.020 us; speedup vs baseline: 1.0985x; 1.0406x over previous
//
#include <hip/hip_runtime.h>
#include <stdint.h>

#define DEV static __device__ __forceinline__

typedef __attribute__((ext_vector_type(8))) __bf16 bf16x8;
typedef __attribute__((ext_vector_type(4))) float f32x4;
typedef __attribute__((ext_vector_type(16))) float f32x16;

// ---------- bf16 helpers ----------
DEV float b2f(unsigned short u) {
    union { unsigned int i; float f; } v; v.i = ((unsigned int)u) << 16; return v.f;
}
DEV unsigned short f2b(float f) {
    unsigned int u = __builtin_bit_cast(unsigned int, f);
    unsigned int r = (u + 0x7FFFu + ((u >> 16) & 1u)) >> 16;  // RNE
    return (unsigned short)r;
}
DEV f32x4 mfma16(bf16x8 a, bf16x8 b, f32x4 c) {
    return __builtin_amdgcn_mfma_f32_16x16x32_bf16(a, b, c, 0, 0, 0);
}
DEV f32x16 mfma32(bf16x8 a, bf16x8 b, f32x16 c) {
    return __builtin_amdgcn_mfma_f32_32x32x16_bf16(a, b, c, 0, 0, 0);
}

// ---------- async global->LDS, 16B per lane ----------
DEV void gload16(const void* g, void* l) {
    __builtin_amdgcn_global_load_lds(
        (const __attribute__((address_space(1))) void*)g,
        (__attribute__((address_space(3))) void*)l, 16, 0, 0);
}

#define VM_WAIT8 asm volatile("s_waitcnt vmcnt(8)" ::: "memory")
#define VM_WAIT4 asm volatile("s_waitcnt vmcnt(4)" ::: "memory")
#define VM_WAIT0 asm volatile("s_waitcnt vmcnt(0)" ::: "memory")

// ============ kernel 0: fp32 -> bf16 copy (n multiple of 2048) ==============
__global__ __launch_bounds__(256) void k_cvt(
    const float* __restrict__ src, unsigned short* __restrict__ dst)
{
    long i = ((long)blockIdx.x * 256 + threadIdx.x) * 8;
    float4 a = *(const float4*)(src + i);
    float4 b = *(const float4*)(src + i + 4);
    union { uint4 v; unsigned short s[8]; } o;
    o.s[0] = f2b(a.x); o.s[1] = f2b(a.y); o.s[2] = f2b(a.z); o.s[3] = f2b(a.w);
    o.s[4] = f2b(b.x); o.s[5] = f2b(b.y); o.s[6] = f2b(b.z); o.s[7] = f2b(b.w);
    *(uint4*)(dst + i) = o.v;
}

// ================== kernel 1: RMSNorm of hidden -> u (bf16) =================
__global__ __launch_bounds__(256) void k_rmsnorm_in(
    const float* __restrict__ h, const float* __restrict__ w,
    unsigned short* __restrict__ u)
{
    int row = blockIdx.x, t = threadIdx.x;
    const float* hp = h + (long)row * 2048 + t * 8;
    float4 a = *(const float4*)hp;
    float4 b = *(const float4*)(hp + 4);
    float x[8] = {a.x, a.y, a.z, a.w, b.x, b.y, b.z, b.w};
    float ss = 0.f;
#pragma unroll
    for (int i = 0; i < 8; i++) ss += x[i] * x[i];
#pragma unroll
    for (int o = 32; o > 0; o >>= 1) ss += __shfl_down(ss, o);
    __shared__ float red[4];
    if ((t & 63) == 0) red[t >> 6] = ss;
    __syncthreads();
    float tot = red[0] + red[1] + red[2] + red[3];
    float scale = rsqrtf(tot * (1.0f / 2048.0f) + 1e-5f);
    float4 wa = *(const float4*)(w + t * 8);
    float4 wb = *(const float4*)(w + t * 8 + 4);
    float wv[8] = {wa.x, wa.y, wa.z, wa.w, wb.x, wb.y, wb.z, wb.w};
    union { uint4 v; unsigned short s[8]; } ow;
#pragma unroll
    for (int i = 0; i < 8; i++) ow.s[i] = f2b(x[i] * scale * wv[i]);
    *(uint4*)(u + (long)row * 2048 + t * 8) = ow.v;
}

// ========== GEMM-256: C[MxN] = A[MxK] * B[NxK]^T, bf16 out (bulk) ===========
// 256x256 tile, BK=32, 8 waves (2x4, wave tile 128x64), 32x32x16 MFMA.
// 4-deep LDS ring (4 x 32KB = 128KB), counted vmcnt (never 0 in steady
// state), ONE raw s_barrier per K-tile, T2 slot-XOR swizzle, T5 setprio.
// Requirements: M%256==0, N%256==0, K%32==0, no clamping (exact tiles).
// Grid: dim3(M/256, N/256). Bijective XCD-chunk swizzle (grid must be %8==0).
__global__ __launch_bounds__(512, 2) void k_gemm256(
    const unsigned short* __restrict__ A, const unsigned short* __restrict__ Bm,
    int K, unsigned short* __restrict__ Cb, int ldc)
{
    __shared__ __align__(16) char sMem[131072];   // 4 bufs x (A 16KB | B 16KB)
    int tid = threadIdx.x;
    int w = tid >> 6, L = tid & 63;

    // ---- XCD-chunked bijective block swizzle (nwg = gx*gy, must be %8) ----
    int nwg = gridDim.x * gridDim.y;
    int cpx = nwg >> 3;
    int fl = blockIdx.y * gridDim.x + blockIdx.x;
    int swz = (fl & 7) * cpx + (fl >> 3);
    long m0 = (long)(swz % gridDim.x) * 256;
    long n0 = (long)(swz / gridDim.x) * 256;

    // ---- staging geometry: thread -> (row, 16B slot), swizzled source ----
    // LDS row = i*128 + (tid>>2), slot = tid&3; dest byte = i*8192 + tid*16.
    // slot-XOR swizzle: phys_slot = logical_slot ^ ((row>>1)&3); DMA writes
    // linear, so SOURCE chunk is pre-swizzled: csw = (tid&3) ^ ((tid>>3)&3).
    int rloc = tid >> 2;                  // 0..127
    int csw = (tid & 3) ^ ((tid >> 3) & 3);
    const unsigned short* gA0 = A + (m0 + rloc) * (long)K + csw * 8;
    const unsigned short* gA1 = A + (m0 + 128 + rloc) * (long)K + csw * 8;
    const unsigned short* gB0 = Bm + (n0 + rloc) * (long)K + csw * 8;
    const unsigned short* gB1 = Bm + (n0 + 128 + rloc) * (long)K + csw * 8;
    int dA0 = tid * 16, dA1 = 8192 + tid * 16;
    int dB0 = 16384 + tid * 16, dB1 = 24576 + tid * 16;

    // ---- fragment read addressing (32x32x16: m/n = L&31, k = (L>>5)*8+j) ---
    int wr = w >> 2, wc = w & 3;          // 2 x 4 wave grid
    int lr = L & 31, lg = L >> 5;
    int xr = ((lr >> 1) & 3) << 4;        // read-side swizzle XOR (bits 4-5)
    int off0 = (lg << 4) ^ xr;            // k-step 0 byte off within 64B row
    int off1 = (32 | (lg << 4)) ^ xr;     // k-step 1
    int aRow = wr * 8192 + lr * 64;       // + mi*2048
    int bRow = 16384 + wc * 4096 + lr * 64;  // + nj*2048

    f32x16 acc[4][2];
#pragma unroll
    for (int mi = 0; mi < 4; mi++)
#pragma unroll
        for (int nj = 0; nj < 2; nj++)
#pragma unroll
            for (int r = 0; r < 16; r++) acc[mi][nj][r] = 0.f;

    // ---- prologue: stage tiles 0,1,2 ----
#pragma unroll
    for (int p = 0; p < 3; ++p) {
        char* db = sMem + p * 32768;
        gload16(gA0, db + dA0); gload16(gA1, db + dA1);
        gload16(gB0, db + dB0); gload16(gB1, db + dB1);
        gA0 += 32; gA1 += 32; gB0 += 32; gB1 += 32;
    }
    VM_WAIT8;                              // tile 0 resident
    __builtin_amdgcn_s_barrier();

    int NT = K >> 5;                       // 64 K-tiles for K=2048
    for (int t = 0; t < NT; ++t) {
        const char* bb = sMem + (t & 3) * 32768;
        char* db = sMem + ((t + 3) & 3) * 32768;
        bool stage = (t < NT - 3);
        // ---- phase A: issue A-half DMA, k-step 0 compute ----
        if (stage) {
            gload16(gA0, db + dA0); gA0 += 32;
            gload16(gA1, db + dA1); gA1 += 32;
        }
        {
            bf16x8 a[4], b[2];
#pragma unroll
            for (int mi = 0; mi < 4; mi++)
                a[mi] = *(const bf16x8*)(bb + aRow + mi * 2048 + off0);
#pragma unroll
            for (int nj = 0; nj < 2; nj++)
                b[nj] = *(const bf16x8*)(bb + bRow + nj * 2048 + off0);
            __builtin_amdgcn_s_setprio(1);
#pragma unroll
            for (int mi = 0; mi < 4; mi++)
#pragma unroll
                for (int nj = 0; nj < 2; nj++)
                    acc[mi][nj] = mfma32(a[mi], b[nj], acc[mi][nj]);
            __builtin_amdgcn_s_setprio(0);
        }
        // ---- phase B: issue B-half DMA, k-step 1 compute ----
        if (stage) {
            gload16(gB0, db + dB0); gB0 += 32;
            gload16(gB1, db + dB1); gB1 += 32;
        }
        {
            bf16x8 a[4], b[2];
#pragma unroll
            for (int mi = 0; mi < 4; mi++)
                a[mi] = *(const bf16x8*)(bb + aRow + mi * 2048 + off1);
#pragma unroll
            for (int nj = 0; nj < 2; nj++)
                b[nj] = *(const bf16x8*)(bb + bRow + nj * 2048 + off1);
            __builtin_amdgcn_s_setprio(1);
#pragma unroll
            for (int mi = 0; mi < 4; mi++)
#pragma unroll
                for (int nj = 0; nj < 2; nj++)
                    acc[mi][nj] = mfma32(a[mi], b[nj], acc[mi][nj]);
            __builtin_amdgcn_s_setprio(0);
        }
        // ---- tile boundary: counted wait (tile t+1 resident), barrier ----
        if (t < NT - 3)       { VM_WAIT8; }
        else if (t == NT - 3) { VM_WAIT4; }
        else if (t == NT - 2) { VM_WAIT0; }
        __builtin_amdgcn_s_barrier();
    }

    // ---- epilogue: C/D layout col=lane&31, row=(r&3)+8*(r>>2)+4*(lane>>5) --
    int colL = L & 31;
    int rL = (L >> 5) * 4;
#pragma unroll
    for (int mi = 0; mi < 4; mi++)
#pragma unroll
        for (int nj = 0; nj < 2; nj++) {
            long c = n0 + wc * 64 + nj * 32 + colL;
#pragma unroll
            for (int r = 0; r < 16; r++) {
                long row = m0 + wr * 128 + mi * 32 + (r & 3) + 8 * (r >> 2) + rL;
                Cb[row * ldc + c] = f2b(acc[mi][nj][r]);
            }
        }
}

// ================== GEMM: C[MxN] = A[MxK] * B[NxK]^T (bf16 in, fp32 acc) ====
// 128x128 tile, BK=64 (128B LDS rows), 4 waves (2x2 of 64x64), 32x32x16 MFMA.
// Used for GEMM2 (fp32 out + residual) and the GEMM1 N-edge strip.
template <int EPI>
__global__ __launch_bounds__(256) void k_gemm_bt(
    const unsigned short* __restrict__ A, const unsigned short* __restrict__ Bm,
    int K, int nvalid, unsigned short* __restrict__ Cb, float* __restrict__ Cf,
    int ldc, const float* __restrict__ Res)
{
    __shared__ __align__(16) unsigned short sA[128 * 64];
    __shared__ __align__(16) unsigned short sB[128 * 64];
    int t = threadIdx.x;
    int w = t >> 6, L = t & 63;

    // ---- supertile swizzle (gy must be multiple of 8; 32 here) ----
    int flat = blockIdx.y * gridDim.x + blockIdx.x;
    int per = gridDim.x * 8;
    int strip = flat / per;
    int rem = flat - strip * per;
    long m0 = (long)(strip * 8 + (rem & 7)) * 128;
    long n0 = (long)(rem >> 3) * 128;

    int rloc = t >> 3;               // 0..31
    int c16  = t & 7;                // 16B chunk within 128B row
    int csw  = c16 ^ (rloc & 7);     // pre-swizzled source chunk
    const unsigned short* gAp[4];
    const unsigned short* gBp[4];
#pragma unroll
    for (int i = 0; i < 4; i++) {
        gAp[i] = A + (m0 + i * 32 + rloc) * (long)K + csw * 8;
        long rb = n0 + i * 32 + rloc;
        if (rb >= nvalid) rb = nvalid - 1;
        gBp[i] = Bm + rb * (long)K + csw * 8;
    }
    unsigned short* lA = sA + t * 8;   // + i*2048 shorts per round
    unsigned short* lB = sB + t * 8;

    int mw = (w >> 1) * 64, nw = (w & 1) * 64;
    int rowA = mw + (L & 31), rowB = nw + (L & 31);
    int swA = (rowA & 7) << 4, swB = (rowB & 7) << 4;
    int q16 = (L >> 5) * 16;          // lane's k-chunk byte offset
    const char* pA = (const char*)sA + rowA * 128;
    const char* pB = (const char*)sB + rowB * 128;

    f32x16 acc[2][2];
#pragma unroll
    for (int ti = 0; ti < 2; ti++)
#pragma unroll
        for (int tj = 0; tj < 2; tj++)
#pragma unroll
            for (int r = 0; r < 16; r++) acc[ti][tj][r] = 0.f;

    for (int kt = 0; kt < K; kt += 64) {
#pragma unroll
        for (int i = 0; i < 4; i++) {
            gload16(gAp[i], lA + i * 2048);
            gload16(gBp[i], lB + i * 2048);
            gAp[i] += 64; gBp[i] += 64;
        }
        __syncthreads();
#pragma unroll
        for (int kk = 0; kk < 4; kk++) {
            bf16x8 af[2], bf[2];
#pragma unroll
            for (int ti = 0; ti < 2; ti++)
                af[ti] = *(const bf16x8*)(pA + ti * 4096 + ((q16 + kk * 32) ^ swA));
#pragma unroll
            for (int tj = 0; tj < 2; tj++)
                bf[tj] = *(const bf16x8*)(pB + tj * 4096 + ((q16 + kk * 32) ^ swB));
#pragma unroll
            for (int ti = 0; ti < 2; ti++)
#pragma unroll
                for (int tj = 0; tj < 2; tj++)
                    acc[ti][tj] = mfma32(af[ti], bf[tj], acc[ti][tj]);
        }
        __syncthreads();
    }
    int colL = L & 31;
    int rL = (L >> 5) * 4;
#pragma unroll
    for (int ti = 0; ti < 2; ti++)
#pragma unroll
        for (int tj = 0; tj < 2; tj++) {
            long c = n0 + nw + tj * 32 + colL;
            if (c >= nvalid) continue;
#pragma unroll
            for (int r = 0; r < 16; r++) {
                long row = m0 + mw + ti * 32 + (r & 3) + 8 * (r >> 2) + rL;
                float v = acc[ti][tj][r];
                if (EPI == 0) Cb[row * ldc + c] = f2b(v);
                else          Cf[row * ldc + c] = v + Res[row * ldc + c];
            }
        }
}

// ======= kernel 4: depthwise causal conv(4) + bias + silu over xBC ==========
__global__ __launch_bounds__(128) void k_conv(
    const unsigned short* __restrict__ zx, const float* __restrict__ cw,
    const float* __restrict__ cb, unsigned short* __restrict__ xbc)
{
    int c = blockIdx.x * 128 + threadIdx.x;   // 0..4223
    int b = blockIdx.z;
    int l0 = blockIdx.y * 64;
    float w0 = cw[c * 4 + 0], w1 = cw[c * 4 + 1];
    float w2 = cw[c * 4 + 2], w3 = cw[c * 4 + 3];
    float bias = cb[c];
    const unsigned short* src = zx + ((long)b * 2048) * 8384 + 4096 + c;
    float xm3 = (l0 >= 3) ? b2f(src[(long)(l0 - 3) * 8384]) : 0.f;
    float xm2 = (l0 >= 2) ? b2f(src[(long)(l0 - 2) * 8384]) : 0.f;
    float xm1 = (l0 >= 1) ? b2f(src[(long)(l0 - 1) * 8384]) : 0.f;
    const unsigned short* s2 = src + (long)l0 * 8384;
    unsigned short* dst = xbc + ((long)(b * 2048 + l0)) * 4224 + c;
#pragma unroll 8
    for (int i = 0; i < 64; i++) {
        float xl = b2f(*s2); s2 += 8384;
        float a = xm3 * w0 + xm2 * w1 + xm1 * w2 + xl * w3 + bias;
        a = a / (1.f + expf(-a));      // silu
        *dst = f2b(a); dst += 4224;
        xm3 = xm2; xm2 = xm1; xm1 = xl;
    }
}

// ============ kernel 5a: per-chunk state via MFMA (pass 1) ==================
__global__ __launch_bounds__(256) void k_chunk_state_mfma(
    const unsigned short* __restrict__ xbc, const unsigned short* __restrict__ zxdt,
    const float* __restrict__ dt_bias, const float* __restrict__ A_log,
    unsigned short* __restrict__ Sbuf, float* __restrict__ dAtot)
{
    int blk = blockIdx.x;
    int c = blk & 7, bh = blk >> 3;
    int b = bh >> 6, h = bh & 63;
    int tid = threadIdx.x;
    int w = tid >> 6, L = tid & 63;
    int quad = L >> 4, col = L & 15;
    int rowBlk = (w >> 1) * 32, colBlk = (w & 1) * 32;
    __shared__ __align__(16) unsigned short sXp[64 * 72];  // X^T (p,t)
    __shared__ __align__(16) unsigned short sBn[64 * 72];  // scaled B^T (n,t)
    __shared__ float sdt[64], sL[64];
    float Ah = expf(A_log[h]);
    float dtb = dt_bias[h];
    f32x4 acc[2][2];
#pragma unroll
    for (int ti = 0; ti < 2; ti++)
#pragma unroll
        for (int tj = 0; tj < 2; tj++) acc[ti][tj] = (f32x4){0.f, 0.f, 0.f, 0.f};
    float sumL = 0.f;

    for (int sub = 0; sub < 4; sub++) {
        int l0 = c * 256 + sub * 64;
        // stage X transposed -> (p,t)
        {
            int t = tid >> 2, pc = tid & 3;
            const unsigned short* gX = xbc + (long)(b * 2048 + l0 + t) * 4224 + h * 64 + pc * 16;
            union { uint4 v; unsigned short s[8]; } x0, x1;
            x0.v = *(const uint4*)gX; x1.v = *(const uint4*)(gX + 8);
#pragma unroll
            for (int j = 0; j < 8; j++) {
                sXp[(pc * 16 + j) * 72 + t] = x0.s[j];
                sXp[(pc * 16 + 8 + j) * 72 + t] = x1.s[j];
            }
        }
        // dt, cumulative log-decay (wave 0)
        if (tid < 64) {
            float raw = b2f(zxdt[((long)(b * 2048 + l0 + tid)) * 8384 + 8320 + h]) + dtb;
            float dtv = (raw > 20.f) ? raw : log1pf(expf(raw));
            float cum = dtv;
#pragma unroll
            for (int off = 1; off < 64; off <<= 1) {
                float v = __shfl_up(cum, off);
                if (tid >= off) cum += v;
            }
            sdt[tid] = dtv;
            sL[tid] = -Ah * cum;
        }
        __syncthreads();
        float Lend = sL[63];
        // stage B transposed & scaled: Bn[n][t] = B[t][n] * dt_t * exp(Lend - L_t)
        {
            int t = tid >> 2, nc = tid & 3;
            float wt = sdt[t] * __expf(Lend - sL[t]);
            const unsigned short* gB = xbc + (long)(b * 2048 + l0 + t) * 4224 + 4096 + nc * 16;
            union { uint4 v; unsigned short s[8]; } x0, x1;
            x0.v = *(const uint4*)gB; x1.v = *(const uint4*)(gB + 8);
#pragma unroll
            for (int j = 0; j < 8; j++) {
                sBn[(nc * 16 + j) * 72 + t] = f2b(b2f(x0.s[j]) * wt);
                sBn[(nc * 16 + 8 + j) * 72 + t] = f2b(b2f(x1.s[j]) * wt);
            }
        }
        __syncthreads();
        float e_end = __expf(Lend);
        sumL += Lend;
#pragma unroll
        for (int ti = 0; ti < 2; ti++)
#pragma unroll
            for (int tj = 0; tj < 2; tj++)
#pragma unroll
                for (int r = 0; r < 4; r++) acc[ti][tj][r] *= e_end;
#pragma unroll
        for (int kb = 0; kb < 2; kb++) {
            bf16x8 ax[2], bx[2];
#pragma unroll
            for (int ti = 0; ti < 2; ti++)
                ax[ti] = *(const bf16x8*)(sXp + (rowBlk + ti * 16 + col) * 72 + kb * 32 + quad * 8);
#pragma unroll
            for (int tj = 0; tj < 2; tj++)
                bx[tj] = *(const bf16x8*)(sBn + (colBlk + tj * 16 + col) * 72 + kb * 32 + quad * 8);
#pragma unroll
            for (int ti = 0; ti < 2; ti++)
#pragma unroll
                for (int tj = 0; tj < 2; tj++)
                    acc[ti][tj] = mfma16(ax[ti], bx[tj], acc[ti][tj]);
        }
        __syncthreads();
    }
#pragma unroll
    for (int ti = 0; ti < 2; ti++)
#pragma unroll
        for (int tj = 0; tj < 2; tj++)
#pragma unroll
            for (int r = 0; r < 4; r++) {
                int p = rowBlk + ti * 16 + quad * 4 + r;
                int n = colBlk + tj * 16 + col;
                Sbuf[(long)blk * 4096 + p * 64 + n] = f2b(acc[ti][tj][r]);
            }
    if (tid == 0) dAtot[blk] = __expf(sumL);
}

// ============ kernel 5b: SSD intra-chunk via MFMA (pass 2) ==================
__global__ __launch_bounds__(256) void k_scan_chunk_mfma(
    const unsigned short* __restrict__ xbc, const unsigned short* __restrict__ zxdt,
    const float* __restrict__ dt_bias, const float* __restrict__ A_log,
    const float* __restrict__ Dv,
    const unsigned short* __restrict__ Sbuf, const float* __restrict__ dAtot,
    unsigned short* __restrict__ yout)
{
    int blk = blockIdx.x;
    int c = blk & 7, bh = blk >> 3;
    int b = bh >> 6, h = bh & 63;
    int tid = threadIdx.x;
    int w = tid >> 6, L = tid & 63;
    int quad = L >> 4, col = L & 15;
    int rowBlk = (w >> 1) * 32, colBlk = (w & 1) * 32;
    __shared__ __align__(16) unsigned short sCm[64 * 72];    // C (s,n)
    __shared__ __align__(16) unsigned short sBtMs[64 * 72];  // B (t,n) -> reused as M (s,t)
    __shared__ __align__(16) unsigned short sXp[64 * 72];    // X^T (p,t)
    __shared__ __align__(16) unsigned short sBn[64 * 72];    // scaled B^T (n,t)
    __shared__ __align__(16) unsigned short sHb[64 * 72];    // H (p,n) bf16
    __shared__ float sdt[64], sL[64], sEs[64];
    float Ah = expf(A_log[h]);
    float dtb = dt_bias[h];
    float Dh = Dv[h];

    f32x4 acc_h[2][2];
#pragma unroll
    for (int ti = 0; ti < 2; ti++)
#pragma unroll
        for (int tj = 0; tj < 2; tj++) acc_h[ti][tj] = (f32x4){0.f, 0.f, 0.f, 0.f};
    int sb = bh * 8;
    for (int j = 0; j < c; j++) {
        float d = dAtot[sb + j];
        const unsigned short* Sp = Sbuf + (long)(sb + j) * 4096;
#pragma unroll
        for (int ti = 0; ti < 2; ti++)
#pragma unroll
            for (int tj = 0; tj < 2; tj++)
#pragma unroll
                for (int r = 0; r < 4; r++) {
                    int p = rowBlk + ti * 16 + quad * 4 + r;
                    int n = colBlk + tj * 16 + col;
                    acc_h[ti][tj][r] = acc_h[ti][tj][r] * d + b2f(Sp[p * 64 + n]);
                }
    }

    for (int sub = 0; sub < 4; sub++) {
        int l0 = c * 256 + sub * 64;
        // (a) stage C (s,n) and B (t,n), stride-72 rows
        {
            int row = tid >> 2, c4 = tid & 3;
            const unsigned short* gR = xbc + (long)(b * 2048 + l0 + row) * 4224;
            uint4 v0 = *(const uint4*)(gR + 4160 + c4 * 8);
            uint4 v1 = *(const uint4*)(gR + 4160 + (c4 + 4) * 8);
            *(uint4*)(sCm + row * 72 + c4 * 8) = v0;
            *(uint4*)(sCm + row * 72 + (c4 + 4) * 8) = v1;
            uint4 w0 = *(const uint4*)(gR + 4096 + c4 * 8);
            uint4 w1 = *(const uint4*)(gR + 4096 + (c4 + 4) * 8);
            *(uint4*)(sBtMs + row * 72 + c4 * 8) = w0;
            *(uint4*)(sBtMs + row * 72 + (c4 + 4) * 8) = w1;
        }
        // stage X transposed
        {
            int t = tid >> 2, pc = tid & 3;
            const unsigned short* gX = xbc + (long)(b * 2048 + l0 + t) * 4224 + h * 64 + pc * 16;
            union { uint4 v; unsigned short s[8]; } x0, x1;
            x0.v = *(const uint4*)gX; x1.v = *(const uint4*)(gX + 8);
#pragma unroll
            for (int j = 0; j < 8; j++) {
                sXp[(pc * 16 + j) * 72 + t] = x0.s[j];
                sXp[(pc * 16 + 8 + j) * 72 + t] = x1.s[j];
            }
        }
        // (b) dt / L / exp(L)
        if (tid < 64) {
            float raw = b2f(zxdt[((long)(b * 2048 + l0 + tid)) * 8384 + 8320 + h]) + dtb;
            float dtv = (raw > 20.f) ? raw : log1pf(expf(raw));
            float cum = dtv;
#pragma unroll
            for (int off = 1; off < 64; off <<= 1) {
                float v = __shfl_up(cum, off);
                if (tid >= off) cum += v;
            }
            sdt[tid] = dtv;
            float l = -Ah * cum;
            sL[tid] = l;
            sEs[tid] = __expf(l);
        }
        __syncthreads();
        float Lend = sL[63];
        // (c) stage scaled-transposed B; write H (bf16) for Ycross
        {
            int t = tid >> 2, nc = tid & 3;
            float wt = sdt[t] * __expf(Lend - sL[t]);
            const unsigned short* gB = xbc + (long)(b * 2048 + l0 + t) * 4224 + 4096 + nc * 16;
            union { uint4 v; unsigned short s[8]; } x0, x1;
            x0.v = *(const uint4*)gB; x1.v = *(const uint4*)(gB + 8);
#pragma unroll
            for (int j = 0; j < 8; j++) {
                sBn[(nc * 16 + j) * 72 + t] = f2b(b2f(x0.s[j]) * wt);
                sBn[(nc * 16 + 8 + j) * 72 + t] = f2b(b2f(x1.s[j]) * wt);
            }
        }
#pragma unroll
        for (int ti = 0; ti < 2; ti++)
#pragma unroll
            for (int tj = 0; tj < 2; tj++)
#pragma unroll
                for (int r = 0; r < 4; r++) {
                    int p = rowBlk + ti * 16 + quad * 4 + r;
                    int n = colBlk + tj * 16 + col;
                    sHb[p * 72 + n] = f2b(acc_h[ti][tj][r]);
                }
        __syncthreads();
        // (d) G = C @ B^T
        f32x4 g[2][2];
#pragma unroll
        for (int ti = 0; ti < 2; ti++)
#pragma unroll
            for (int tj = 0; tj < 2; tj++) g[ti][tj] = (f32x4){0.f, 0.f, 0.f, 0.f};
#pragma unroll
        for (int kb = 0; kb < 2; kb++) {
            bf16x8 ac[2], bc[2];
#pragma unroll
            for (int ti = 0; ti < 2; ti++)
                ac[ti] = *(const bf16x8*)(sCm + (rowBlk + ti * 16 + col) * 72 + kb * 32 + quad * 8);
#pragma unroll
            for (int tj = 0; tj < 2; tj++)
                bc[tj] = *(const bf16x8*)(sBtMs + (colBlk + tj * 16 + col) * 72 + kb * 32 + quad * 8);
#pragma unroll
            for (int ti = 0; ti < 2; ti++)
#pragma unroll
                for (int tj = 0; tj < 2; tj++)
                    g[ti][tj] = mfma16(ac[ti], bc[tj], g[ti][tj]);
        }
        __syncthreads();   // all waves done reading B before overwrite as M
        // (e) mask + decay -> M (s,t) into sBtMs
#pragma unroll
        for (int tj = 0; tj < 2; tj++) {
            int t_idx = colBlk + tj * 16 + col;
            float lt = sL[t_idx], dtt = sdt[t_idx];
#pragma unroll
            for (int ti = 0; ti < 2; ti++)
#pragma unroll
                for (int r = 0; r < 4; r++) {
                    int s_idx = rowBlk + ti * 16 + quad * 4 + r;
                    float m = (t_idx <= s_idx) ? g[ti][tj][r] * dtt * __expf(sL[s_idx] - lt) : 0.f;
                    sBtMs[s_idx * 72 + t_idx] = f2b(m);
                }
        }
        __syncthreads();
        // (f) Y = M @ X + (es*C) @ H^T
        f32x4 yv[2][2];
#pragma unroll
        for (int ti = 0; ti < 2; ti++)
#pragma unroll
            for (int tj = 0; tj < 2; tj++) yv[ti][tj] = (f32x4){0.f, 0.f, 0.f, 0.f};
#pragma unroll
        for (int kb = 0; kb < 2; kb++) {
            bf16x8 am[2], bxp[2];
#pragma unroll
            for (int ti = 0; ti < 2; ti++)
                am[ti] = *(const bf16x8*)(sBtMs + (rowBlk + ti * 16 + col) * 72 + kb * 32 + quad * 8);
#pragma unroll
            for (int tj = 0; tj < 2; tj++)
                bxp[tj] = *(const bf16x8*)(sXp + (colBlk + tj * 16 + col) * 72 + kb * 32 + quad * 8);
#pragma unroll
            for (int ti = 0; ti < 2; ti++)
#pragma unroll
                for (int tj = 0; tj < 2; tj++)
                    yv[ti][tj] = mfma16(am[ti], bxp[tj], yv[ti][tj]);
        }
        float es0 = sEs[rowBlk + col], es1 = sEs[rowBlk + 16 + col];
#pragma unroll
        for (int kb = 0; kb < 2; kb++) {
            bf16x8 acx[2], bhh[2];
#pragma unroll
            for (int ti = 0; ti < 2; ti++) {
                union { bf16x8 v; unsigned short s[8]; } a;
                a.v = *(const bf16x8*)(sCm + (rowBlk + ti * 16 + col) * 72 + kb * 32 + quad * 8);
                float es = ti ? es1 : es0;
#pragma unroll
                for (int j = 0; j < 8; j++) a.s[j] = f2b(b2f(a.s[j]) * es);
                acx[ti] = a.v;
            }
#pragma unroll
            for (int tj = 0; tj < 2; tj++)
                bhh[tj] = *(const bf16x8*)(sHb + (colBlk + tj * 16 + col) * 72 + kb * 32 + quad * 8);
#pragma unroll
            for (int ti = 0; ti < 2; ti++)
#pragma unroll
                for (int tj = 0; tj < 2; tj++)
                    yv[ti][tj] = mfma16(acx[ti], bhh[tj], yv[ti][tj]);
        }
        // (g) H = e_end*H + Xw^T @ B
        float e_end = __expf(Lend);
#pragma unroll
        for (int ti = 0; ti < 2; ti++)
#pragma unroll
            for (int tj = 0; tj < 2; tj++)
#pragma unroll
                for (int r = 0; r < 4; r++) acc_h[ti][tj][r] *= e_end;
#pragma unroll
        for (int kb = 0; kb < 2; kb++) {
            bf16x8 ax[2], bn[2];
#pragma unroll
            for (int ti = 0; ti < 2; ti++)
                ax[ti] = *(const bf16x8*)(sXp + (rowBlk + ti * 16 + col) * 72 + kb * 32 + quad * 8);
#pragma unroll
            for (int tj = 0; tj < 2; tj++)
                bn[tj] = *(const bf16x8*)(sBn + (colBlk + tj * 16 + col) * 72 + kb * 32 + quad * 8);
#pragma unroll
            for (int ti = 0; ti < 2; ti++)
#pragma unroll
                for (int tj = 0; tj < 2; tj++)
                    acc_h[ti][tj] = mfma16(ax[ti], bn[tj], acc_h[ti][tj]);
        }
        // (h) y epilogue: + D*x, store bf16
#pragma unroll
        for (int ti = 0; ti < 2; ti++)
#pragma unroll
            for (int tj = 0; tj < 2; tj++)
#pragma unroll
                for (int r = 0; r < 4; r++) {
                    int s_idx = rowBlk + ti * 16 + quad * 4 + r;
                    int p = colBlk + tj * 16 + col;
                    float xv = b2f(sXp[p * 72 + s_idx]);
                    float yo = yv[ti][tj][r] + Dh * xv;
                    yout[((long)(b * 2048 + l0 + s_idx)) * 8384 + 4096 + h * 64 + p] = f2b(yo);
                }
        __syncthreads();   // protect LDS reuse next sub-chunk
    }
}

// ====== kernel 6: gated RMSNorm: y2 = rmsnorm(y * silu(z)) * norm_w (bf16) ==
__global__ __launch_bounds__(256) void k_gatenorm(
    const unsigned short* __restrict__ zx, const float* __restrict__ nw,
    unsigned short* __restrict__ y2)
{
    int row = blockIdx.x, t = threadIdx.x;
    const unsigned short* zr = zx + (long)row * 8384;
    float v[16]; float ss = 0.f;
#pragma unroll
    for (int i = 0; i < 16; i++) {
        int c = t + i * 256;
        float z = b2f(zr[c]);
        float y = b2f(zr[4096 + c]);
        float g = y * (z / (1.f + expf(-z)));
        v[i] = g; ss += g * g;
    }
#pragma unroll
    for (int o = 32; o > 0; o >>= 1) ss += __shfl_down(ss, o);
    __shared__ float red[4];
    if ((t & 63) == 0) red[t >> 6] = ss;
    __syncthreads();
    float tot = red[0] + red[1] + red[2] + red[3];
    float scale = rsqrtf(tot * (1.0f / 4096.0f) + 1e-5f);
#pragma unroll
    for (int i = 0; i < 16; i++) {
        int c = t + i * 256;
        y2[(long)row * 4096 + c] = f2b(v[i] * scale * nw[c]);
    }
}

// ============================= launcher =====================================
extern "C" void kernel_launch(void* const* d_in, const int* in_sizes, int n_in,
                              void* d_out, int out_size, void* d_ws, size_t ws_size,
                              hipStream_t stream)
{
    const float* h    = (const float*)d_in[0]; // (2,2048,2048)
    const float* rmsw = (const float*)d_in[1]; // (2048)
    const float* w1   = (const float*)d_in[2]; // (8384,2048)
    const float* cw   = (const float*)d_in[3]; // (4224,4)
    const float* cbp  = (const float*)d_in[4]; // (4224)
    const float* dtb  = (const float*)d_in[5]; // (64)
    const float* alog = (const float*)d_in[6]; // (64)
    const float* Dv   = (const float*)d_in[7]; // (64)
    const float* nw   = (const float*)d_in[8]; // (4096)
    const float* w2   = (const float*)d_in[9]; // (2048,4096)

    char* ws = (char*)d_ws;
    // ws layout (peak 120,061,952 B — identical to prior passing layout):
    //   [0, 68681728): zx bf16 4096x8384 (scan writes y into cols 4096..8192)
    //   [68681728, 103284736): w1b bf16 -> xbc bf16 4096x4224 -> y2 bf16
    //   [103284736, 111673344): Sbuf bf16 1024x4096
    //   [111673344, +4096):     dAt fp32 1024
    //   [103284736, 120061952): u before GEMM1; w2b after scan (Sbuf/dAt dead)
    unsigned short* zx    = (unsigned short*)ws;
    unsigned short* w1b   = (unsigned short*)(ws + 68681728L);
    unsigned short* xbc   = (unsigned short*)(ws + 68681728L);
    unsigned short* y2    = (unsigned short*)(ws + 68681728L);
    unsigned short* u     = (unsigned short*)(ws + 103284736L);
    unsigned short* Sbuf  = (unsigned short*)(ws + 103284736L);
    float*          dAt   = (float*)(ws + 111673344L);
    unsigned short* w2b   = (unsigned short*)(ws + 103284736L);
    float* outp = (float*)d_out;

    k_rmsnorm_in<<<4096, 256, 0, stream>>>(h, rmsw, u);
    k_cvt<<<8384, 256, 0, stream>>>(w1, w1b);
    // zx = u @ w1b^T : bulk cols 0..8191 with 256^2 pipelined kernel
    k_gemm256<<<dim3(16, 32), 512, 0, stream>>>(u, w1b, 2048, zx, 8384);
    // edge strip cols 8192..8383 (192 valid) with 128^2 kernel
    k_gemm_bt<0><<<dim3(2, 32), 256, 0, stream>>>(
        u, w1b + 8192L * 2048, 2048, 192, zx + 8192, nullptr, 8384, nullptr);
    k_conv<<<dim3(33, 32, 2), 128, 0, stream>>>(zx, cw, cbp, xbc);
    k_chunk_state_mfma<<<1024, 256, 0, stream>>>(xbc, zx, dtb, alog, Sbuf, dAt);
    k_scan_chunk_mfma<<<1024, 256, 0, stream>>>(xbc, zx, dtb, alog, Dv, Sbuf, dAt, zx);
    k_gatenorm<<<4096, 256, 0, stream>>>(zx, nw, y2);
    k_cvt<<<4096, 256, 0, stream>>>(w2, w2b);
    // out = y2 @ w2b^T + residual : M=4096, N=2048, K=4096, fp32 out
    k_gemm_bt<1><<<dim3(16, 32), 256, 0, stream>>>(y2, w2b, 4096, 2048, nullptr, outp, 2048, h);
}

// Round 4
// 514.077 us; speedup vs baseline: 1.1347x; 1.0330x over previous
//
#include <hip/hip_runtime.h>
#include <stdint.h>

#define DEV static __device__ __forceinline__

typedef __attribute__((ext_vector_type(8))) __bf16 bf16x8;
typedef __attribute__((ext_vector_type(4))) float f32x4;
typedef __attribute__((ext_vector_type(16))) float f32x16;

// ---------- bf16 helpers ----------
DEV float b2f(unsigned short u) {
    union { unsigned int i; float f; } v; v.i = ((unsigned int)u) << 16; return v.f;
}
DEV unsigned short f2b(float f) {
    unsigned int u = __builtin_bit_cast(unsigned int, f);
    unsigned int r = (u + 0x7FFFu + ((u >> 16) & 1u)) >> 16;  // RNE
    return (unsigned short)r;
}
DEV f32x4 mfma16(bf16x8 a, bf16x8 b, f32x4 c) {
    return __builtin_amdgcn_mfma_f32_16x16x32_bf16(a, b, c, 0, 0, 0);
}
DEV f32x16 mfma32(bf16x8 a, bf16x8 b, f32x16 c) {
    return __builtin_amdgcn_mfma_f32_32x32x16_bf16(a, b, c, 0, 0, 0);
}

// ---------- async global->LDS, 16B per lane ----------
DEV void gload16(const void* g, void* l) {
    __builtin_amdgcn_global_load_lds(
        (const __attribute__((address_space(1))) void*)g,
        (__attribute__((address_space(3))) void*)l, 16, 0, 0);
}

// ============ kernel 0: fp32 -> bf16 copy (n multiple of 2048) ==============
__global__ __launch_bounds__(256) void k_cvt(
    const float* __restrict__ src, unsigned short* __restrict__ dst)
{
    long i = ((long)blockIdx.x * 256 + threadIdx.x) * 8;
    float4 a = *(const float4*)(src + i);
    float4 b = *(const float4*)(src + i + 4);
    union { uint4 v; unsigned short s[8]; } o;
    o.s[0] = f2b(a.x); o.s[1] = f2b(a.y); o.s[2] = f2b(a.z); o.s[3] = f2b(a.w);
    o.s[4] = f2b(b.x); o.s[5] = f2b(b.y); o.s[6] = f2b(b.z); o.s[7] = f2b(b.w);
    *(uint4*)(dst + i) = o.v;
}

// ================== kernel 1: RMSNorm of hidden -> u (bf16) =================
__global__ __launch_bounds__(256) void k_rmsnorm_in(
    const float* __restrict__ h, const float* __restrict__ w,
    unsigned short* __restrict__ u)
{
    int row = blockIdx.x, t = threadIdx.x;
    const float* hp = h + (long)row * 2048 + t * 8;
    float4 a = *(const float4*)hp;
    float4 b = *(const float4*)(hp + 4);
    float x[8] = {a.x, a.y, a.z, a.w, b.x, b.y, b.z, b.w};
    float ss = 0.f;
#pragma unroll
    for (int i = 0; i < 8; i++) ss += x[i] * x[i];
#pragma unroll
    for (int o = 32; o > 0; o >>= 1) ss += __shfl_down(ss, o);
    __shared__ float red[4];
    if ((t & 63) == 0) red[t >> 6] = ss;
    __syncthreads();
    float tot = red[0] + red[1] + red[2] + red[3];
    float scale = rsqrtf(tot * (1.0f / 2048.0f) + 1e-5f);
    float4 wa = *(const float4*)(w + t * 8);
    float4 wb = *(const float4*)(w + t * 8 + 4);
    float wv[8] = {wa.x, wa.y, wa.z, wa.w, wb.x, wb.y, wb.z, wb.w};
    union { uint4 v; unsigned short s[8]; } ow;
#pragma unroll
    for (int i = 0; i < 8; i++) ow.s[i] = f2b(x[i] * scale * wv[i]);
    *(uint4*)(u + (long)row * 2048 + t * 8) = ow.v;
}

// ========== GEMM-256: C[MxN] = A[MxK] * B[NxK]^T, bf16 out (bulk) ===========
// m201-style 8-phase schedule. 256x256 tile, 8 waves (2M x 4N, wave tile
// 128x64), 16x16x32 MFMA, K64 tiles, iter = 2 K-tiles = 8 phases.
// LDS = 2 K-tile buffers x (A 32KB | B 32KB) = 128KB; 128B rows; phys 16B
// slot = logical ^ (row&7) on BOTH the DMA source (pre-swizzle) and reads.
// REGION-DEATH LEDGER (fixed from R3's race): every DS_A/DS_B touches BOTH
// 16KB halves of its region (wr/wc wave split). Deaths: buf0.B after P2,
// buf0.A after P3, buf1.B after P6, buf1.A after P7. Stages:
//   P1: ktB.A1 | P2: none | P3: kt2.B0 | P4: kt2.B1 + vmcnt(4)
//   P5: kt2.A0 | P6: kt2.A1 | P7: kt3.B0 | P8: kt3.B1 + kt3.A0 + vmcnt(6)
// Last iter: P4 -> vmcnt(0) (tail stages guarded off).
// Requirements: M%256==0, N%256==0, K%128==0, grid (M/256, N/256), %8==0.
__global__ __launch_bounds__(512, 2) void k_gemm256(
    const unsigned short* __restrict__ A, const unsigned short* __restrict__ Bm,
    int K, unsigned short* __restrict__ Cb, int ldc)
{
    __shared__ __align__(16) char lds[131072];
    int tid = threadIdx.x;
    int w = tid >> 6, l = tid & 63;
    int NT = K >> 6, NI = K >> 7;
    long Kb = (long)K * 2;

    // ---- XCD-chunked bijective block swizzle ----
    int nwg = gridDim.x * gridDim.y;
    int cpx = nwg >> 3;
    int fl = blockIdx.y * gridDim.x + blockIdx.x;
    int swz = (fl & 7) * cpx + (fl >> 3);
    long m0 = (long)(swz % gridDim.x) * 256;
    long n0 = (long)(swz / gridDim.x) * 256;

    // ---- staging addressing: linear LDS dest, pre-swizzled source ----
    int rl = tid >> 3;                       // 0..63 (row within 64-row round)
    int csw16 = (((tid & 7) ^ (rl & 7)) << 4);
    const char* pA0 = (const char*)A + (m0 + rl) * Kb + csw16;
    const char* pA1 = (const char*)A + (m0 + 64 + rl) * Kb + csw16;
    const char* pB0 = (const char*)Bm + (n0 + rl) * Kb + csw16;
    const char* pB1 = (const char*)Bm + (n0 + 64 + rl) * Kb + csw16;
    int ldst = tid * 16;

    // stage one half-tile (128 rows x 128B) = 2 gloads/thread
#define STG(P0, P1, RGN, kt, half) do { if ((kt) < NT) {                      \
    char* Lr_ = lds + (((kt) & 1) << 16) + (RGN) + ((half) << 14);            \
    long go_ = (long)(half) * 128 * Kb + (long)(kt) * 128;                    \
    gload16((P0) + go_, Lr_ + ldst);                                          \
    gload16((P1) + go_, Lr_ + 8192 + ldst); } } while (0)

    // ---- fragment read addressing (16x16x32: m/n = l&15, k16B = l>>4) ----
    int lq = l >> 4, lr15 = l & 15, key = l & 7;
    int off0 = ((lq ^ key) << 4);            // k-step 0, swizzled slot
    int off1 = (((4 + lq) ^ key) << 4);      // k-step 1
    int aB = ((w >> 2) * 128 + lr15) * 128;
    int bB = 32768 + (((w & 3) * 64 + lr15) * 128);

    bf16x8 aF[4][2], b0F[2][2], b1F[2][2];
    f32x4 acc[8][4];
#pragma unroll
    for (int s = 0; s < 8; s++)
#pragma unroll
        for (int t = 0; t < 4; t++) acc[s][t] = (f32x4){0.f, 0.f, 0.f, 0.f};

#define DS_A(mh, BUF) do {                                                    \
    const char* ba_ = lds + (BUF) + aB + (mh) * 8192;                         \
    _Pragma("unroll") for (int s_ = 0; s_ < 4; s_++) {                        \
        aF[s_][0] = *(const bf16x8*)(ba_ + s_ * 2048 + off0);                 \
        aF[s_][1] = *(const bf16x8*)(ba_ + s_ * 2048 + off1); } } while (0)

#define DS_B(DST, nh, BUF) do {                                               \
    const char* bb_ = lds + (BUF) + bB + (nh) * 4096;                         \
    _Pragma("unroll") for (int t_ = 0; t_ < 2; t_++) {                        \
        DST[t_][0] = *(const bf16x8*)(bb_ + t_ * 2048 + off0);                \
        DST[t_][1] = *(const bf16x8*)(bb_ + t_ * 2048 + off1); } } while (0)

#define MQ(mh, nh, BF) do {                                                   \
    __builtin_amdgcn_s_setprio(1);                                            \
    _Pragma("unroll") for (int kk_ = 0; kk_ < 2; kk_++)                       \
    _Pragma("unroll") for (int s_ = 0; s_ < 4; s_++)                          \
    _Pragma("unroll") for (int t_ = 0; t_ < 2; t_++)                          \
        acc[(mh) * 4 + s_][(nh) * 2 + t_] =                                   \
            mfma16(aF[s_][kk_], BF[t_][kk_], acc[(mh) * 4 + s_][(nh) * 2 + t_]); \
    __builtin_amdgcn_s_setprio(0); } while (0)

#define BAR __builtin_amdgcn_s_barrier()
#define LG0 do { asm volatile("s_waitcnt lgkmcnt(0)" ::: "memory");           \
                 __builtin_amdgcn_sched_barrier(0); } while (0)

    // ---- prologue: kt0 full {A0,A1,B0,B1}; kt1 {B0,B1,A0} (A1 at iter0 P1) -
    STG(pA0, pA1, 0,     0, 0);
    STG(pA0, pA1, 0,     0, 1);
    STG(pB0, pB1, 32768, 0, 0);
    STG(pB0, pB1, 32768, 0, 1);
    STG(pB0, pB1, 32768, 1, 0);
    STG(pB0, pB1, 32768, 1, 1);
    STG(pA0, pA1, 0,     1, 0);
    asm volatile("s_waitcnt vmcnt(6)" ::: "memory");   // kt0 fully resident
    BAR;

    for (int it = 0; it < NI; ++it) {
        int k1 = 2 * it + 1, k2 = 2 * it + 2, k3 = 2 * it + 3;
        // P1: ktA (m0,n0); stage ktB.A1 (buf1.A last read prev-P7)
        DS_A(0, 0); DS_B(b0F, 0, 0);
        STG(pA0, pA1, 0, k1, 1);
        BAR; LG0; MQ(0, 0, b0F); BAR;
        // P2: (m0,n1); no stage (no dead region yet)
        DS_B(b1F, 1, 0);
        BAR; LG0; MQ(0, 1, b1F); BAR;
        // P3: (m1,n1); stage kt+2.B0 (buf0.B dead after P2)
        DS_A(1, 0);
        STG(pB0, pB1, 32768, k2, 0);
        BAR; LG0; MQ(1, 1, b1F); BAR;
        // P4: (m1,n0); stage kt+2.B1; wait: ktB fully resident
        STG(pB0, pB1, 32768, k2, 1);
        BAR; MQ(1, 0, b0F);
        if (it == NI - 1) { asm volatile("s_waitcnt vmcnt(0)" ::: "memory"); }
        else              { asm volatile("s_waitcnt vmcnt(4)" ::: "memory"); }
        BAR;
        // P5: ktB (m0,n0); stage kt+2.A0 (buf0.A dead after P3)
        DS_A(0, 65536); DS_B(b0F, 0, 65536);
        STG(pA0, pA1, 0, k2, 0);
        BAR; LG0; MQ(0, 0, b0F); BAR;
        // P6: (m0,n1); stage kt+2.A1
        DS_B(b1F, 1, 65536);
        STG(pA0, pA1, 0, k2, 1);
        BAR; LG0; MQ(0, 1, b1F); BAR;
        // P7: (m1,n1); stage kt+3.B0 (buf1.B dead after P6)
        DS_A(1, 65536);
        STG(pB0, pB1, 32768, k3, 0);
        BAR; LG0; MQ(1, 1, b1F); BAR;
        // P8: (m1,n0); stage kt+3.B1 + kt+3.A0 (buf1.A dead after P7)
        STG(pB0, pB1, 32768, k3, 1);
        STG(pA0, pA1, 0, k3, 0);
        BAR; MQ(1, 0, b0F);
        if (it < NI - 1) { asm volatile("s_waitcnt vmcnt(6)" ::: "memory"); }
        BAR;
    }

    // ---- epilogue: mfma16 C/D layout col = l&15, row = (l>>4)*4 + r ----
    int colb = (w & 3) * 64 + lr15;
    int rowb = (w >> 2) * 128 + lq * 4;
#pragma unroll
    for (int s = 0; s < 8; s++)
#pragma unroll
        for (int t = 0; t < 4; t++) {
            long col = n0 + colb + t * 16;
            long row = m0 + rowb + s * 16;
#pragma unroll
            for (int r = 0; r < 4; r++)
                Cb[(row + r) * ldc + col] = f2b(acc[s][t][r]);
        }
#undef STG
#undef DS_A
#undef DS_B
#undef MQ
#undef BAR
#undef LG0
}

// ================== GEMM: C[MxN] = A[MxK] * B[NxK]^T (bf16 in, fp32 acc) ====
// 128x128 tile, BK=64 (128B LDS rows), 4 waves (2x2 of 64x64), 32x32x16 MFMA.
// Used for GEMM2 (fp32 out + residual) and the GEMM1 N-edge strip.
template <int EPI>
__global__ __launch_bounds__(256) void k_gemm_bt(
    const unsigned short* __restrict__ A, const unsigned short* __restrict__ Bm,
    int K, int nvalid, unsigned short* __restrict__ Cb, float* __restrict__ Cf,
    int ldc, const float* __restrict__ Res)
{
    __shared__ __align__(16) unsigned short sA[128 * 64];
    __shared__ __align__(16) unsigned short sB[128 * 64];
    int t = threadIdx.x;
    int w = t >> 6, L = t & 63;

    // ---- supertile swizzle (gy must be multiple of 8; 32 here) ----
    int flat = blockIdx.y * gridDim.x + blockIdx.x;
    int per = gridDim.x * 8;
    int strip = flat / per;
    int rem = flat - strip * per;
    long m0 = (long)(strip * 8 + (rem & 7)) * 128;
    long n0 = (long)(rem >> 3) * 128;

    int rloc = t >> 3;               // 0..31
    int c16  = t & 7;                // 16B chunk within 128B row
    int csw  = c16 ^ (rloc & 7);     // pre-swizzled source chunk
    const unsigned short* gAp[4];
    const unsigned short* gBp[4];
#pragma unroll
    for (int i = 0; i < 4; i++) {
        gAp[i] = A + (m0 + i * 32 + rloc) * (long)K + csw * 8;
        long rb = n0 + i * 32 + rloc;
        if (rb >= nvalid) rb = nvalid - 1;
        gBp[i] = Bm + rb * (long)K + csw * 8;
    }
    unsigned short* lA = sA + t * 8;   // + i*2048 shorts per round
    unsigned short* lB = sB + t * 8;

    int mw = (w >> 1) * 64, nw = (w & 1) * 64;
    int rowA = mw + (L & 31), rowB = nw + (L & 31);
    int swA = (rowA & 7) << 4, swB = (rowB & 7) << 4;
    int q16 = (L >> 5) * 16;          // lane's k-chunk byte offset
    const char* pA = (const char*)sA + rowA * 128;
    const char* pB = (const char*)sB + rowB * 128;

    f32x16 acc[2][2];
#pragma unroll
    for (int ti = 0; ti < 2; ti++)
#pragma unroll
        for (int tj = 0; tj < 2; tj++)
#pragma unroll
            for (int r = 0; r < 16; r++) acc[ti][tj][r] = 0.f;

    for (int kt = 0; kt < K; kt += 64) {
#pragma unroll
        for (int i = 0; i < 4; i++) {
            gload16(gAp[i], lA + i * 2048);
            gload16(gBp[i], lB + i * 2048);
            gAp[i] += 64; gBp[i] += 64;
        }
        __syncthreads();
#pragma unroll
        for (int kk = 0; kk < 4; kk++) {
            bf16x8 af[2], bf[2];
#pragma unroll
            for (int ti = 0; ti < 2; ti++)
                af[ti] = *(const bf16x8*)(pA + ti * 4096 + ((q16 + kk * 32) ^ swA));
#pragma unroll
            for (int tj = 0; tj < 2; tj++)
                bf[tj] = *(const bf16x8*)(pB + tj * 4096 + ((q16 + kk * 32) ^ swB));
#pragma unroll
            for (int ti = 0; ti < 2; ti++)
#pragma unroll
                for (int tj = 0; tj < 2; tj++)
                    acc[ti][tj] = mfma32(af[ti], bf[tj], acc[ti][tj]);
        }
        __syncthreads();
    }
    int colL = L & 31;
    int rL = (L >> 5) * 4;
#pragma unroll
    for (int ti = 0; ti < 2; ti++)
#pragma unroll
        for (int tj = 0; tj < 2; tj++) {
            long c = n0 + nw + tj * 32 + colL;
            if (c >= nvalid) continue;
#pragma unroll
            for (int r = 0; r < 16; r++) {
                long row = m0 + mw + ti * 32 + (r & 3) + 8 * (r >> 2) + rL;
                float v = acc[ti][tj][r];
                if (EPI == 0) Cb[row * ldc + c] = f2b(v);
                else          Cf[row * ldc + c] = v + Res[row * ldc + c];
            }
        }
}

// ======= kernel 4: depthwise causal conv(4) + bias + silu over xBC ==========
__global__ __launch_bounds__(128) void k_conv(
    const unsigned short* __restrict__ zx, const float* __restrict__ cw,
    const float* __restrict__ cb, unsigned short* __restrict__ xbc)
{
    int c = blockIdx.x * 128 + threadIdx.x;   // 0..4223
    int b = blockIdx.z;
    int l0 = blockIdx.y * 64;
    float w0 = cw[c * 4 + 0], w1 = cw[c * 4 + 1];
    float w2 = cw[c * 4 + 2], w3 = cw[c * 4 + 3];
    float bias = cb[c];
    const unsigned short* src = zx + ((long)b * 2048) * 8384 + 4096 + c;
    float xm3 = (l0 >= 3) ? b2f(src[(long)(l0 - 3) * 8384]) : 0.f;
    float xm2 = (l0 >= 2) ? b2f(src[(long)(l0 - 2) * 8384]) : 0.f;
    float xm1 = (l0 >= 1) ? b2f(src[(long)(l0 - 1) * 8384]) : 0.f;
    const unsigned short* s2 = src + (long)l0 * 8384;
    unsigned short* dst = xbc + ((long)(b * 2048 + l0)) * 4224 + c;
#pragma unroll 8
    for (int i = 0; i < 64; i++) {
        float xl = b2f(*s2); s2 += 8384;
        float a = xm3 * w0 + xm2 * w1 + xm1 * w2 + xl * w3 + bias;
        a = a / (1.f + expf(-a));      // silu
        *dst = f2b(a); dst += 4224;
        xm3 = xm2; xm2 = xm1; xm1 = xl;
    }
}

// ============ kernel 5a: per-chunk state via MFMA (pass 1) ==================
__global__ __launch_bounds__(256) void k_chunk_state_mfma(
    const unsigned short* __restrict__ xbc, const unsigned short* __restrict__ zxdt,
    const float* __restrict__ dt_bias, const float* __restrict__ A_log,
    unsigned short* __restrict__ Sbuf, float* __restrict__ dAtot)
{
    int blk = blockIdx.x;
    int c = blk & 7, bh = blk >> 3;
    int b = bh >> 6, h = bh & 63;
    int tid = threadIdx.x;
    int w = tid >> 6, L = tid & 63;
    int quad = L >> 4, col = L & 15;
    int rowBlk = (w >> 1) * 32, colBlk = (w & 1) * 32;
    __shared__ __align__(16) unsigned short sXp[64 * 72];  // X^T (p,t)
    __shared__ __align__(16) unsigned short sBn[64 * 72];  // scaled B^T (n,t)
    __shared__ float sdt[64], sL[64];
    float Ah = expf(A_log[h]);
    float dtb = dt_bias[h];
    f32x4 acc[2][2];
#pragma unroll
    for (int ti = 0; ti < 2; ti++)
#pragma unroll
        for (int tj = 0; tj < 2; tj++) acc[ti][tj] = (f32x4){0.f, 0.f, 0.f, 0.f};
    float sumL = 0.f;

    for (int sub = 0; sub < 4; sub++) {
        int l0 = c * 256 + sub * 64;
        // stage X transposed -> (p,t)
        {
            int t = tid >> 2, pc = tid & 3;
            const unsigned short* gX = xbc + (long)(b * 2048 + l0 + t) * 4224 + h * 64 + pc * 16;
            union { uint4 v; unsigned short s[8]; } x0, x1;
            x0.v = *(const uint4*)gX; x1.v = *(const uint4*)(gX + 8);
#pragma unroll
            for (int j = 0; j < 8; j++) {
                sXp[(pc * 16 + j) * 72 + t] = x0.s[j];
                sXp[(pc * 16 + 8 + j) * 72 + t] = x1.s[j];
            }
        }
        // dt, cumulative log-decay (wave 0)
        if (tid < 64) {
            float raw = b2f(zxdt[((long)(b * 2048 + l0 + tid)) * 8384 + 8320 + h]) + dtb;
            float dtv = (raw > 20.f) ? raw : log1pf(expf(raw));
            float cum = dtv;
#pragma unroll
            for (int off = 1; off < 64; off <<= 1) {
                float v = __shfl_up(cum, off);
                if (tid >= off) cum += v;
            }
            sdt[tid] = dtv;
            sL[tid] = -Ah * cum;
        }
        __syncthreads();
        float Lend = sL[63];
        // stage B transposed & scaled: Bn[n][t] = B[t][n] * dt_t * exp(Lend - L_t)
        {
            int t = tid >> 2, nc = tid & 3;
            float wt = sdt[t] * __expf(Lend - sL[t]);
            const unsigned short* gB = xbc + (long)(b * 2048 + l0 + t) * 4224 + 4096 + nc * 16;
            union { uint4 v; unsigned short s[8]; } x0, x1;
            x0.v = *(const uint4*)gB; x1.v = *(const uint4*)(gB + 8);
#pragma unroll
            for (int j = 0; j < 8; j++) {
                sBn[(nc * 16 + j) * 72 + t] = f2b(b2f(x0.s[j]) * wt);
                sBn[(nc * 16 + 8 + j) * 72 + t] = f2b(b2f(x1.s[j]) * wt);
            }
        }
        __syncthreads();
        float e_end = __expf(Lend);
        sumL += Lend;
#pragma unroll
        for (int ti = 0; ti < 2; ti++)
#pragma unroll
            for (int tj = 0; tj < 2; tj++)
#pragma unroll
                for (int r = 0; r < 4; r++) acc[ti][tj][r] *= e_end;
#pragma unroll
        for (int kb = 0; kb < 2; kb++) {
            bf16x8 ax[2], bx[2];
#pragma unroll
            for (int ti = 0; ti < 2; ti++)
                ax[ti] = *(const bf16x8*)(sXp + (rowBlk + ti * 16 + col) * 72 + kb * 32 + quad * 8);
#pragma unroll
            for (int tj = 0; tj < 2; tj++)
                bx[tj] = *(const bf16x8*)(sBn + (colBlk + tj * 16 + col) * 72 + kb * 32 + quad * 8);
#pragma unroll
            for (int ti = 0; ti < 2; ti++)
#pragma unroll
                for (int tj = 0; tj < 2; tj++)
                    acc[ti][tj] = mfma16(ax[ti], bx[tj], acc[ti][tj]);
        }
        __syncthreads();
    }
#pragma unroll
    for (int ti = 0; ti < 2; ti++)
#pragma unroll
        for (int tj = 0; tj < 2; tj++)
#pragma unroll
            for (int r = 0; r < 4; r++) {
                int p = rowBlk + ti * 16 + quad * 4 + r;
                int n = colBlk + tj * 16 + col;
                Sbuf[(long)blk * 4096 + p * 64 + n] = f2b(acc[ti][tj][r]);
            }
    if (tid == 0) dAtot[blk] = __expf(sumL);
}

// ============ kernel 5b: SSD intra-chunk via MFMA (pass 2) ==================
__global__ __launch_bounds__(256) void k_scan_chunk_mfma(
    const unsigned short* __restrict__ xbc, const unsigned short* __restrict__ zxdt,
    const float* __restrict__ dt_bias, const float* __restrict__ A_log,
    const float* __restrict__ Dv,
    const unsigned short* __restrict__ Sbuf, const float* __restrict__ dAtot,
    unsigned short* __restrict__ yout)
{
    int blk = blockIdx.x;
    int c = blk & 7, bh = blk >> 3;
    int b = bh >> 6, h = bh & 63;
    int tid = threadIdx.x;
    int w = tid >> 6, L = tid & 63;
    int quad = L >> 4, col = L & 15;
    int rowBlk = (w >> 1) * 32, colBlk = (w & 1) * 32;
    __shared__ __align__(16) unsigned short sCm[64 * 72];    // C (s,n)
    __shared__ __align__(16) unsigned short sBtMs[64 * 72];  // B (t,n) -> reused as M (s,t)
    __shared__ __align__(16) unsigned short sXp[64 * 72];    // X^T (p,t)
    __shared__ __align__(16) unsigned short sBn[64 * 72];    // scaled B^T (n,t)
    __shared__ __align__(16) unsigned short sHb[64 * 72];    // H (p,n) bf16
    __shared__ float sdt[64], sL[64], sEs[64];
    float Ah = expf(A_log[h]);
    float dtb = dt_bias[h];
    float Dh = Dv[h];

    f32x4 acc_h[2][2];
#pragma unroll
    for (int ti = 0; ti < 2; ti++)
#pragma unroll
        for (int tj = 0; tj < 2; tj++) acc_h[ti][tj] = (f32x4){0.f, 0.f, 0.f, 0.f};
    int sb = bh * 8;
    for (int j = 0; j < c; j++) {
        float d = dAtot[sb + j];
        const unsigned short* Sp = Sbuf + (long)(sb + j) * 4096;
#pragma unroll
        for (int ti = 0; ti < 2; ti++)
#pragma unroll
            for (int tj = 0; tj < 2; tj++)
#pragma unroll
                for (int r = 0; r < 4; r++) {
                    int p = rowBlk + ti * 16 + quad * 4 + r;
                    int n = colBlk + tj * 16 + col;
                    acc_h[ti][tj][r] = acc_h[ti][tj][r] * d + b2f(Sp[p * 64 + n]);
                }
    }

    for (int sub = 0; sub < 4; sub++) {
        int l0 = c * 256 + sub * 64;
        // (a) stage C (s,n) and B (t,n), stride-72 rows
        {
            int row = tid >> 2, c4 = tid & 3;
            const unsigned short* gR = xbc + (long)(b * 2048 + l0 + row) * 4224;
            uint4 v0 = *(const uint4*)(gR + 4160 + c4 * 8);
            uint4 v1 = *(const uint4*)(gR + 4160 + (c4 + 4) * 8);
            *(uint4*)(sCm + row * 72 + c4 * 8) = v0;
            *(uint4*)(sCm + row * 72 + (c4 + 4) * 8) = v1;
            uint4 w0 = *(const uint4*)(gR + 4096 + c4 * 8);
            uint4 w1 = *(const uint4*)(gR + 4096 + (c4 + 4) * 8);
            *(uint4*)(sBtMs + row * 72 + c4 * 8) = w0;
            *(uint4*)(sBtMs + row * 72 + (c4 + 4) * 8) = w1;
        }
        // stage X transposed
        {
            int t = tid >> 2, pc = tid & 3;
            const unsigned short* gX = xbc + (long)(b * 2048 + l0 + t) * 4224 + h * 64 + pc * 16;
            union { uint4 v; unsigned short s[8]; } x0, x1;
            x0.v = *(const uint4*)gX; x1.v = *(const uint4*)(gX + 8);
#pragma unroll
            for (int j = 0; j < 8; j++) {
                sXp[(pc * 16 + j) * 72 + t] = x0.s[j];
                sXp[(pc * 16 + 8 + j) * 72 + t] = x1.s[j];
            }
        }
        // (b) dt / L / exp(L)
        if (tid < 64) {
            float raw = b2f(zxdt[((long)(b * 2048 + l0 + tid)) * 8384 + 8320 + h]) + dtb;
            float dtv = (raw > 20.f) ? raw : log1pf(expf(raw));
            float cum = dtv;
#pragma unroll
            for (int off = 1; off < 64; off <<= 1) {
                float v = __shfl_up(cum, off);
                if (tid >= off) cum += v;
            }
            sdt[tid] = dtv;
            float l = -Ah * cum;
            sL[tid] = l;
            sEs[tid] = __expf(l);
        }
        __syncthreads();
        float Lend = sL[63];
        // (c) stage scaled-transposed B; write H (bf16) for Ycross
        {
            int t = tid >> 2, nc = tid & 3;
            float wt = sdt[t] * __expf(Lend - sL[t]);
            const unsigned short* gB = xbc + (long)(b * 2048 + l0 + t) * 4224 + 4096 + nc * 16;
            union { uint4 v; unsigned short s[8]; } x0, x1;
            x0.v = *(const uint4*)gB; x1.v = *(const uint4*)(gB + 8);
#pragma unroll
            for (int j = 0; j < 8; j++) {
                sBn[(nc * 16 + j) * 72 + t] = f2b(b2f(x0.s[j]) * wt);
                sBn[(nc * 16 + 8 + j) * 72 + t] = f2b(b2f(x1.s[j]) * wt);
            }
        }
#pragma unroll
        for (int ti = 0; ti < 2; ti++)
#pragma unroll
            for (int tj = 0; tj < 2; tj++)
#pragma unroll
                for (int r = 0; r < 4; r++) {
                    int p = rowBlk + ti * 16 + quad * 4 + r;
                    int n = colBlk + tj * 16 + col;
                    sHb[p * 72 + n] = f2b(acc_h[ti][tj][r]);
                }
        __syncthreads();
        // (d) G = C @ B^T
        f32x4 g[2][2];
#pragma unroll
        for (int ti = 0; ti < 2; ti++)
#pragma unroll
            for (int tj = 0; tj < 2; tj++) g[ti][tj] = (f32x4){0.f, 0.f, 0.f, 0.f};
#pragma unroll
        for (int kb = 0; kb < 2; kb++) {
            bf16x8 ac[2], bc[2];
#pragma unroll
            for (int ti = 0; ti < 2; ti++)
                ac[ti] = *(const bf16x8*)(sCm + (rowBlk + ti * 16 + col) * 72 + kb * 32 + quad * 8);
#pragma unroll
            for (int tj = 0; tj < 2; tj++)
                bc[tj] = *(const bf16x8*)(sBtMs + (colBlk + tj * 16 + col) * 72 + kb * 32 + quad * 8);
#pragma unroll
            for (int ti = 0; ti < 2; ti++)
#pragma unroll
                for (int tj = 0; tj < 2; tj++)
                    g[ti][tj] = mfma16(ac[ti], bc[tj], g[ti][tj]);
        }
        __syncthreads();   // all waves done reading B before overwrite as M
        // (e) mask + decay -> M (s,t) into sBtMs
#pragma unroll
        for (int tj = 0; tj < 2; tj++) {
            int t_idx = colBlk + tj * 16 + col;
            float lt = sL[t_idx], dtt = sdt[t_idx];
#pragma unroll
            for (int ti = 0; ti < 2; ti++)
#pragma unroll
                for (int r = 0; r < 4; r++) {
                    int s_idx = rowBlk + ti * 16 + quad * 4 + r;
                    float m = (t_idx <= s_idx) ? g[ti][tj][r] * dtt * __expf(sL[s_idx] - lt) : 0.f;
                    sBtMs[s_idx * 72 + t_idx] = f2b(m);
                }
        }
        __syncthreads();
        // (f) Y = M @ X + (es*C) @ H^T
        f32x4 yv[2][2];
#pragma unroll
        for (int ti = 0; ti < 2; ti++)
#pragma unroll
            for (int tj = 0; tj < 2; tj++) yv[ti][tj] = (f32x4){0.f, 0.f, 0.f, 0.f};
#pragma unroll
        for (int kb = 0; kb < 2; kb++) {
            bf16x8 am[2], bxp[2];
#pragma unroll
            for (int ti = 0; ti < 2; ti++)
                am[ti] = *(const bf16x8*)(sBtMs + (rowBlk + ti * 16 + col) * 72 + kb * 32 + quad * 8);
#pragma unroll
            for (int tj = 0; tj < 2; tj++)
                bxp[tj] = *(const bf16x8*)(sXp + (colBlk + tj * 16 + col) * 72 + kb * 32 + quad * 8);
#pragma unroll
            for (int ti = 0; ti < 2; ti++)
#pragma unroll
                for (int tj = 0; tj < 2; tj++)
                    yv[ti][tj] = mfma16(am[ti], bxp[tj], yv[ti][tj]);
        }
        float es0 = sEs[rowBlk + col], es1 = sEs[rowBlk + 16 + col];
#pragma unroll
        for (int kb = 0; kb < 2; kb++) {
            bf16x8 acx[2], bhh[2];
#pragma unroll
            for (int ti = 0; ti < 2; ti++) {
                union { bf16x8 v; unsigned short s[8]; } a;
                a.v = *(const bf16x8*)(sCm + (rowBlk + ti * 16 + col) * 72 + kb * 32 + quad * 8);
                float es = ti ? es1 : es0;
#pragma unroll
                for (int j = 0; j < 8; j++) a.s[j] = f2b(b2f(a.s[j]) * es);
                acx[ti] = a.v;
            }
#pragma unroll
            for (int tj = 0; tj < 2; tj++)
                bhh[tj] = *(const bf16x8*)(sHb + (colBlk + tj * 16 + col) * 72 + kb * 32 + quad * 8);
#pragma unroll
            for (int ti = 0; ti < 2; ti++)
#pragma unroll
                for (int tj = 0; tj < 2; tj++)
                    yv[ti][tj] = mfma16(acx[ti], bhh[tj], yv[ti][tj]);
        }
        // (g) H = e_end*H + Xw^T @ B
        float e_end = __expf(Lend);
#pragma unroll
        for (int ti = 0; ti < 2; ti++)
#pragma unroll
            for (int tj = 0; tj < 2; tj++)
#pragma unroll
                for (int r = 0; r < 4; r++) acc_h[ti][tj][r] *= e_end;
#pragma unroll
        for (int kb = 0; kb < 2; kb++) {
            bf16x8 ax[2], bn[2];
#pragma unroll
            for (int ti = 0; ti < 2; ti++)
                ax[ti] = *(const bf16x8*)(sXp + (rowBlk + ti * 16 + col) * 72 + kb * 32 + quad * 8);
#pragma unroll
            for (int tj = 0; tj < 2; tj++)
                bn[tj] = *(const bf16x8*)(sBn + (colBlk + tj * 16 + col) * 72 + kb * 32 + quad * 8);
#pragma unroll
            for (int ti = 0; ti < 2; ti++)
#pragma unroll
                for (int tj = 0; tj < 2; tj++)
                    acc_h[ti][tj] = mfma16(ax[ti], bn[tj], acc_h[ti][tj]);
        }
        // (h) y epilogue: + D*x, store bf16
#pragma unroll
        for (int ti = 0; ti < 2; ti++)
#pragma unroll
            for (int tj = 0; tj < 2; tj++)
#pragma unroll
                for (int r = 0; r < 4; r++) {
                    int s_idx = rowBlk + ti * 16 + quad * 4 + r;
                    int p = colBlk + tj * 16 + col;
                    float xv = b2f(sXp[p * 72 + s_idx]);
                    float yo = yv[ti][tj][r] + Dh * xv;
                    yout[((long)(b * 2048 + l0 + s_idx)) * 8384 + 4096 + h * 64 + p] = f2b(yo);
                }
        __syncthreads();   // protect LDS reuse next sub-chunk
    }
}

// ====== kernel 6: gated RMSNorm: y2 = rmsnorm(y * silu(z)) * norm_w (bf16) ==
__global__ __launch_bounds__(256) void k_gatenorm(
    const unsigned short* __restrict__ zx, const float* __restrict__ nw,
    unsigned short* __restrict__ y2)
{
    int row = blockIdx.x, t = threadIdx.x;
    const unsigned short* zr = zx + (long)row * 8384;
    float v[16]; float ss = 0.f;
#pragma unroll
    for (int i = 0; i < 16; i++) {
        int c = t + i * 256;
        float z = b2f(zr[c]);
        float y = b2f(zr[4096 + c]);
        float g = y * (z / (1.f + expf(-z)));
        v[i] = g; ss += g * g;
    }
#pragma unroll
    for (int o = 32; o > 0; o >>= 1) ss += __shfl_down(ss, o);
    __shared__ float red[4];
    if ((t & 63) == 0) red[t >> 6] = ss;
    __syncthreads();
    float tot = red[0] + red[1] + red[2] + red[3];
    float scale = rsqrtf(tot * (1.0f / 4096.0f) + 1e-5f);
#pragma unroll
    for (int i = 0; i < 16; i++) {
        int c = t + i * 256;
        y2[(long)row * 4096 + c] = f2b(v[i] * scale * nw[c]);
    }
}

// ============================= launcher =====================================
extern "C" void kernel_launch(void* const* d_in, const int* in_sizes, int n_in,
                              void* d_out, int out_size, void* d_ws, size_t ws_size,
                              hipStream_t stream)
{
    const float* h    = (const float*)d_in[0]; // (2,2048,2048)
    const float* rmsw = (const float*)d_in[1]; // (2048)
    const float* w1   = (const float*)d_in[2]; // (8384,2048)
    const float* cw   = (const float*)d_in[3]; // (4224,4)
    const float* cbp  = (const float*)d_in[4]; // (4224)
    const float* dtb  = (const float*)d_in[5]; // (64)
    const float* alog = (const float*)d_in[6]; // (64)
    const float* Dv   = (const float*)d_in[7]; // (64)
    const float* nw   = (const float*)d_in[8]; // (4096)
    const float* w2   = (const float*)d_in[9]; // (2048,4096)

    char* ws = (char*)d_ws;
    // ws layout (peak 120,061,952 B — identical to prior passing layout):
    //   [0, 68681728): zx bf16 4096x8384 (scan writes y into cols 4096..8192)
    //   [68681728, 103284736): w1b bf16 -> xbc bf16 4096x4224 -> y2 bf16
    //   [103284736, 111673344): Sbuf bf16 1024x4096
    //   [111673344, +4096):     dAt fp32 1024
    //   [103284736, 120061952): u before GEMM1; w2b after scan (Sbuf/dAt dead)
    unsigned short* zx    = (unsigned short*)ws;
    unsigned short* w1b   = (unsigned short*)(ws + 68681728L);
    unsigned short* xbc   = (unsigned short*)(ws + 68681728L);
    unsigned short* y2    = (unsigned short*)(ws + 68681728L);
    unsigned short* u     = (unsigned short*)(ws + 103284736L);
    unsigned short* Sbuf  = (unsigned short*)(ws + 103284736L);
    float*          dAt   = (float*)(ws + 111673344L);
    unsigned short* w2b   = (unsigned short*)(ws + 103284736L);
    float* outp = (float*)d_out;

    k_rmsnorm_in<<<4096, 256, 0, stream>>>(h, rmsw, u);
    k_cvt<<<8384, 256, 0, stream>>>(w1, w1b);
    // zx = u @ w1b^T : bulk cols 0..8191 with 256^2 8-phase kernel
    k_gemm256<<<dim3(16, 32), 512, 0, stream>>>(u, w1b, 2048, zx, 8384);
    // edge strip cols 8192..8383 (192 valid) with 128^2 kernel
    k_gemm_bt<0><<<dim3(2, 32), 256, 0, stream>>>(
        u, w1b + 8192L * 2048, 2048, 192, zx + 8192, nullptr, 8384, nullptr);
    k_conv<<<dim3(33, 32, 2), 128, 0, stream>>>(zx, cw, cbp, xbc);
    k_chunk_state_mfma<<<1024, 256, 0, stream>>>(xbc, zx, dtb, alog, Sbuf, dAt);
    k_scan_chunk_mfma<<<1024, 256, 0, stream>>>(xbc, zx, dtb, alog, Dv, Sbuf, dAt, zx);
    k_gatenorm<<<4096, 256, 0, stream>>>(zx, nw, y2);
    k_cvt<<<4096, 256, 0, stream>>>(w2, w2b);
    // out = y2 @ w2b^T + residual : M=4096, N=2048, K=4096, fp32 out
    k_gemm_bt<1><<<dim3(16, 32), 256, 0, stream>>>(y2, w2b, 4096, 2048, nullptr, outp, 2048, h);
}